// Round 8
// baseline (197.005 us; speedup 1.0000x reference)
//
#include <hip/hip_runtime.h>

typedef unsigned short u16;
typedef unsigned int u32;
typedef __bf16 bf16x8 __attribute__((ext_vector_type(8)));
typedef float f32x4 __attribute__((ext_vector_type(4)));
typedef unsigned short u16x4 __attribute__((ext_vector_type(4)));

#define LOG2E 1.4426950408889634f

#if __has_builtin(__builtin_amdgcn_exp2f)
#define EXP2F(x) __builtin_amdgcn_exp2f(x)
#else
#define EXP2F(x) exp2f(x)
#endif

__device__ __forceinline__ u16 f2bf(float f) {
    union { float f; u32 u; } a; a.f = f;
    u32 u = a.u;
    u += 0x7FFFu + ((u >> 16) & 1u);   // RNE (finite inputs)
    return (u16)(u >> 16);
}
__device__ __forceinline__ bf16x8 ldg8(const u16* p) {
    return *reinterpret_cast<const bf16x8*>(p);
}
#if __has_builtin(__builtin_amdgcn_cvt_pk_bf16_f32)
__device__ __forceinline__ u32 pack2(float a, float b) {
    auto r = __builtin_amdgcn_cvt_pk_bf16_f32(a, b);   // v_cvt_pk_bf16_f32
    return __builtin_bit_cast(u32, r);
}
#else
__device__ __forceinline__ u32 pack2(float a, float b) {
    u32 ua = __float_as_uint(a) + 0x8000u;
    u32 ub = __float_as_uint(b) + 0x8000u;
    return __builtin_amdgcn_perm(ub, ua, 0x07060302);
}
#endif
// async global -> LDS, 16 B per lane. LDS dest = wave-uniform base + lane*16.
__device__ __forceinline__ void async16(const void* g, void* l) {
    __builtin_amdgcn_global_load_lds(
        (const __attribute__((address_space(1))) u32*)g,
        (__attribute__((address_space(3))) u32*)l, 16, 0, 0);
}

#define MFMA16(a, b, c) __builtin_amdgcn_mfma_f32_16x16x32_bf16((a), (b), (c), 0, 0, 0)

// ---------------------------------------------------------------------------
// Fused prep: y<8 -> transpose X tile; y in 8..11 -> pack weight matrix;
// y==12 -> lqw * log2(e) into global fp32 (4 blocks). Grid (64, 13).
// ---------------------------------------------------------------------------
__global__ __launch_bounds__(256) void prep(const float* __restrict__ X,
                                            u16* __restrict__ Xt,
                                            const float* __restrict__ s0,
                                            const float* __restrict__ s1,
                                            const float* __restrict__ s2,
                                            const float* __restrict__ s3,
                                            u16* __restrict__ Wqkv,
                                            u16* __restrict__ Wp,
                                            const float* __restrict__ lqw,
                                            float* __restrict__ lqw2g) {
    __shared__ u16 tile[64][65];
    const int tid = threadIdx.x;
    const int y = blockIdx.y;

    if (y < 8) {                                  // transpose 64x64 tile
        const int t0 = blockIdx.x * 64;
        const int c0 = y * 64;
#pragma unroll
        for (int i = 0; i < 16; ++i) {
            int idx = tid + i * 256;
            int r = idx >> 6, cc = idx & 63;
            tile[r][cc] = f2bf(X[(size_t)(c0 + r) * 4096 + t0 + cc]);
        }
        __syncthreads();
#pragma unroll
        for (int i = 0; i < 16; ++i) {
            int idx = tid + i * 256;
            int tr = idx >> 6, cc = idx & 63;
            Xt[(size_t)(t0 + tr) * 512 + c0 + cc] = tile[cc][tr];
        }
    } else if (y < 12) {                          // pack one 512x512 weight
        const int m = y - 8;
        const float* s = (m == 0) ? s0 : (m == 1) ? s1 : (m == 2) ? s2 : s3;
        u16* d = (m == 3) ? Wp : Wqkv + (size_t)m * 262144;
#pragma unroll
        for (int j = 0; j < 4; ++j) {
            int i = blockIdx.x * 1024 + j * 256 + tid;
            float4 v = reinterpret_cast<const float4*>(s)[i];
            u16x4 o;
            o[0] = f2bf(v.x); o[1] = f2bf(v.y); o[2] = f2bf(v.z); o[3] = f2bf(v.w);
            reinterpret_cast<u16x4*>(d)[i] = o;
        }
    } else {                                      // lqw * LOG2E (1024 float4)
        if (blockIdx.x < 4) {
            int i = blockIdx.x * 256 + tid;
            float4 v = reinterpret_cast<const float4*>(lqw)[i];
            v.x *= LOG2E; v.y *= LOG2E; v.z *= LOG2E; v.w *= LOG2E;
            reinterpret_cast<float4*>(lqw2g)[i] = v;
        }
    }
}

// ---------------------------------------------------------------------------
// Fused QKV GEMM, LDS-staged (unchanged, known-good).
// ---------------------------------------------------------------------------
__global__ __launch_bounds__(512, 2) void qkv_gemm(const u16* __restrict__ Wqkv,
                                                   const u16* __restrict__ Xt,
                                                   const float* __restrict__ qb,
                                                   const float* __restrict__ kb,
                                                   const float* __restrict__ vb,
                                                   u16* __restrict__ Qt,
                                                   u16* __restrict__ Kt,
                                                   u16* __restrict__ Vp) {
    __shared__ __align__(16) u16 Al[2][128 * 32];
    __shared__ __align__(16) u16 Bl[2][128 * 32];

    const int tid = threadIdx.x;
    const int w = tid >> 6, lane = tid & 63;
    const int quad = lane >> 4, lm = lane & 15;
    const int wm = w & 1, wn = w >> 1;
    const int n0 = blockIdx.x * 128;
    const int my = blockIdx.y;
    const int m0 = my * 128;

    const int arow = lane >> 2;
    const int sch = (lane & 3) ^ ((lane >> 3) & 3);   // source chunk (XOR on row>>1)
    const u16* agp = Wqkv + (size_t)(m0 + w * 16 + arow) * 512 + sch * 8;
    const u16* bgp = Xt + (size_t)(n0 + w * 16 + arow) * 512 + sch * 8;

    async16(agp, &Al[0][w * 16 * 32]);
    async16(bgp, &Bl[0][w * 16 * 32]);
    agp += 32; bgp += 32;

    const int FOFF = lm * 64 + ((quad ^ ((lm >> 1) & 3)) << 4);

    f32x4 acc[4][2];
#pragma unroll
    for (int mt = 0; mt < 4; ++mt)
#pragma unroll
        for (int bt = 0; bt < 2; ++bt) acc[mt][bt] = (f32x4){0.f, 0.f, 0.f, 0.f};

    __syncthreads();

    for (int s = 0; s < 16; ++s) {
        const int buf = s & 1;
        if (s < 15) {
            async16(agp, &Al[buf ^ 1][w * 16 * 32]);
            async16(bgp, &Bl[buf ^ 1][w * 16 * 32]);
            agp += 32; bgp += 32;
        }
        const char* Ab = (const char*)&Al[buf][0];
        const char* Bb = (const char*)&Bl[buf][0];
        bf16x8 af[4], bfr[2];
#pragma unroll
        for (int mt = 0; mt < 4; ++mt)
            af[mt] = *(const bf16x8*)(Ab + wm * 4096 + mt * 1024 + FOFF);
#pragma unroll
        for (int bt = 0; bt < 2; ++bt)
            bfr[bt] = *(const bf16x8*)(Bb + wn * 2048 + bt * 1024 + FOFF);
#pragma unroll
        for (int mt = 0; mt < 4; ++mt)
#pragma unroll
            for (int bt = 0; bt < 2; ++bt)
                acc[mt][bt] = MFMA16(af[mt], bfr[bt], acc[mt][bt]);
        __syncthreads();
    }

    const int mat = my >> 2;                     // 0=Q, 1=K, 2=V
    const float* bias = (mat == 0) ? qb : (mat == 1) ? kb : vb;
    const int chbase = (my & 3) * 128 + wm * 64 + quad * 4;

    if (mat < 2) {
        u16* out = mat ? Kt : Qt;
        const float sc = mat ? 1.0f : 0.125f * LOG2E;
#pragma unroll
        for (int mt = 0; mt < 4; ++mt) {
            const int ch = chbase + mt * 16;
            float4 bv = *(const float4*)(bias + ch);
            float bvf[4] = {bv.x, bv.y, bv.z, bv.w};
#pragma unroll
            for (int bt = 0; bt < 2; ++bt) {
                int tok = n0 + wn * 32 + bt * 16 + lm;
                u16x4 pk;
#pragma unroll
                for (int r = 0; r < 4; ++r)
                    pk[r] = f2bf((acc[mt][bt][r] + bvf[r]) * sc);
                *(u16x4*)(out + (size_t)tok * 512 + ch) = pk;
            }
        }
    } else {
#pragma unroll
        for (int mt = 0; mt < 4; ++mt) {
            const int ch = chbase + mt * 16;
            float4 bv = *(const float4*)(bias + ch);
            float bvf[4] = {bv.x, bv.y, bv.z, bv.w};
#pragma unroll
            for (int bt = 0; bt < 2; ++bt) {
                int g = bt * 16 + lm;
                int col = n0 + wn * 32 + 8 * ((g >> 2) & 3) + 4 * ((g >> 4) & 1) + (g & 3);
#pragma unroll
                for (int r = 0; r < 4; ++r)
                    Vp[(size_t)(ch + r) * 4096 + col] = f2bf(acc[mt][bt][r] + bvf[r]);
            }
        }
    }
}

// ---------------------------------------------------------------------------
// Output projection, LDS-staged (unchanged, known-good).
// ---------------------------------------------------------------------------
__global__ __launch_bounds__(256, 2) void out_gemm(const u16* __restrict__ Wp,
                                                   const u16* __restrict__ Ot,
                                                   const float* __restrict__ pb,
                                                   float* __restrict__ out) {
    __shared__ __align__(16) u16 Al[2][128 * 32];
    __shared__ __align__(16) u16 Bl[2][64 * 32];

    const int tid = threadIdx.x;
    const int w = tid >> 6, lane = tid & 63;
    const int quad = lane >> 4, lm = lane & 15;
    const int wm = w & 1, wn = w >> 1;
    const int n0 = blockIdx.x * 64;
    const int m0 = blockIdx.y * 128;

    const int arow = lane >> 2;
    const int sch = (lane & 3) ^ ((lane >> 3) & 3);
    const u16* agp0 = Wp + (size_t)(m0 + w * 16 + arow) * 512 + sch * 8;
    const u16* agp1 = agp0 + (size_t)64 * 512;
    const u16* bgp = Ot + (size_t)(n0 + w * 16 + arow) * 512 + sch * 8;

    async16(agp0, &Al[0][w * 16 * 32]);
    async16(agp1, &Al[0][(64 + w * 16) * 32]);
    async16(bgp, &Bl[0][w * 16 * 32]);
    agp0 += 32; agp1 += 32; bgp += 32;

    const int FOFF = lm * 64 + ((quad ^ ((lm >> 1) & 3)) << 4);

    f32x4 acc[4][2];
#pragma unroll
    for (int mt = 0; mt < 4; ++mt)
#pragma unroll
        for (int bt = 0; bt < 2; ++bt) acc[mt][bt] = (f32x4){0.f, 0.f, 0.f, 0.f};

    __syncthreads();

    for (int s = 0; s < 16; ++s) {
        const int buf = s & 1;
        if (s < 15) {
            async16(agp0, &Al[buf ^ 1][w * 16 * 32]);
            async16(agp1, &Al[buf ^ 1][(64 + w * 16) * 32]);
            async16(bgp, &Bl[buf ^ 1][w * 16 * 32]);
            agp0 += 32; agp1 += 32; bgp += 32;
        }
        const char* Ab = (const char*)&Al[buf][0];
        const char* Bb = (const char*)&Bl[buf][0];
        bf16x8 af[4], bfr[2];
#pragma unroll
        for (int mt = 0; mt < 4; ++mt)
            af[mt] = *(const bf16x8*)(Ab + wm * 4096 + mt * 1024 + FOFF);
#pragma unroll
        for (int bt = 0; bt < 2; ++bt)
            bfr[bt] = *(const bf16x8*)(Bb + wn * 2048 + bt * 1024 + FOFF);
#pragma unroll
        for (int mt = 0; mt < 4; ++mt)
#pragma unroll
            for (int bt = 0; bt < 2; ++bt)
                acc[mt][bt] = MFMA16(af[mt], bfr[bt], acc[mt][bt]);
        __syncthreads();
    }

#pragma unroll
    for (int mt = 0; mt < 4; ++mt) {
        const int ch = m0 + wm * 64 + mt * 16 + quad * 4;
        float4 bv = *(const float4*)(pb + ch);
        float bvf[4] = {bv.x, bv.y, bv.z, bv.w};
#pragma unroll
        for (int bt = 0; bt < 2; ++bt) {
            int tok = n0 + wn * 32 + bt * 16 + lm;
#pragma unroll
            for (int r = 0; r < 4; ++r)
                out[(size_t)(ch + r) * 4096 + tok] = acc[mt][bt][r] + bvf[r];
        }
    }
}

// ---------------------------------------------------------------------------
// Flash attention v7: 16-QUERY WAVES — real register margin for 4 waves/SIMD.
// R7 post-mortem: v6's honest tally was ~126 regs vs the 128 cap of
// launch_bounds(512,4); compiler slop -> ~13 dwords/thread spilled
// (WRITE_SIZE 32 MB, MfmaUtil 13%). Occupancy mechanism held (38%).
// v7 = v6 with the per-wave query tile halved to 16 q (1 MFMA subtile):
// acc 16 + bq 8 + vf 16 + k 16 + bb 4 + breg 8 + psum 1 + temps/addr ~28
// ~= 97 regs -> ~30 regs slack. Grid 2048 blocks (256 q-groups x 8 heads,
// head-clustered h=bid&7), 512 thr = 8 waves, wave = 16 q x 512 keys
// (split-K=8, 16 x 32-key steps), K LDS dbuf (8 KB/wave, 64 KB/block),
// V direct-from-L2, zero in-loop barriers, identical vmcnt ledger to v6:
// prologue [Q2, b2, K0(4), K1(4)]; body0 wait(4); steady wait(6); t15
// wait(2). WRITE_SIZE ~4 MB is the no-spill sentinel; if no-spill but
// still ~48 us, the occupancy theory is falsified -> revert to R4.
// ---------------------------------------------------------------------------
#define WAITVM(N) asm volatile("s_waitcnt vmcnt(" #N ")" ::: "memory")

__global__ __launch_bounds__(512, 4) void flash_attn(const u16* __restrict__ Qt,
                                                     const u16* __restrict__ Kt,
                                                     const u16* __restrict__ Vp,
                                                     const float* __restrict__ lqw2g,
                                                     u16* __restrict__ Ot) {
    __shared__ __align__(16) char smem[65536];

    const int tid = threadIdx.x;
    const int w = tid >> 6, lane = tid & 63;         // w = 0..7 (key eighth)
    const int quad = lane >> 4, lm = lane & 15;
    const int bid = blockIdx.x;
    const int h = bid & 7, hq = h * 64;              // head -> XCD cluster
    const int q0 = (bid >> 3) * 16;
    const int kstart = w * 512;

    char* kvw = smem + w * 8192;                     // private K dbuf (2 x 4 KB)

    // K staging (XOR swizzle at global source, LDS linear)
    const int srow = lane >> 3;                      // 0..7
    const int schunk = (lane & 7) ^ srow;
    const u16* kg = Kt + (size_t)(kstart + srow) * 512 + hq + schunk * 8;

    // V fragment base (direct-global; proven layout)
    const u16* vp = Vp + (size_t)(hq + lm) * 4096 + kstart + quad * 8;

    // Q fragments: 1 subtile x 2 d-halves (2 vmem loads)
    const u16* qb = Qt + (size_t)(q0 + lm) * 512 + hq + quad * 8;
    const bf16x8 bq0 = ldg8(qb);
    const bf16x8 bq1 = ldg8(qb + 32);

    // bias prefetch registers (2 vmem loads)
    f32x4 breg0 = *(const f32x4*)(lqw2g + kstart + quad * 4);
    f32x4 breg1 = *(const f32x4*)(lqw2g + kstart + 16 + quad * 4);
    const float* bptr = lqw2g + kstart + 32 + quad * 4;

    // K fragment read offsets (proven layout)
    const int A0 = lm * 128 + ((quad ^ (lm & 7)) << 4);       // d 0..31
    const int A1 = A0 ^ 64;                                   // d 32..63

#define STAGEK(DST)                                                            \
    {                                                                          \
        char* nb = (DST);                                                      \
        async16(kg, nb);                                                       \
        async16(kg + 8 * 512, nb + 1024);                                      \
        async16(kg + 16 * 512, nb + 2048);                                     \
        async16(kg + 24 * 512, nb + 3072);                                     \
        kg += 32 * 512;                                                        \
    }

    // stage K tiles 0 and 1
    STAGEK(kvw)
    STAGEK(kvw + 4096)

    f32x4 acc_o[4];                                   // [d-group]
#pragma unroll
    for (int mt = 0; mt < 4; ++mt) acc_o[mt] = (f32x4){0.f, 0.f, 0.f, 0.f};
    float psum = 0.f;

    int bufsel = 0;

#define BODY(WN, DOBIAS, DOSTAGE)                                              \
    {                                                                          \
        WAITVM(WN);                                                            \
        bf16x8 vf0 = ldg8(vp);                                                 \
        bf16x8 vf1 = ldg8(vp + (size_t)16 * 4096);                             \
        bf16x8 vf2 = ldg8(vp + (size_t)32 * 4096);                             \
        bf16x8 vf3 = ldg8(vp + (size_t)48 * 4096);                             \
        vp += 32;                                                              \
        const char* Kb = kvw + bufsel;                                         \
        bf16x8 k00 = *(const bf16x8*)(Kb + A0);                                \
        bf16x8 k01 = *(const bf16x8*)(Kb + A1);                                \
        bf16x8 k10 = *(const bf16x8*)(Kb + 2048 + A0);                         \
        bf16x8 k11 = *(const bf16x8*)(Kb + 2048 + A1);                         \
        union { u32 u[4]; bf16x8 v; } bb;                                      \
        {                                                                      \
            f32x4 a = MFMA16(k00, bq0, breg0);                                 \
            a = MFMA16(k01, bq1, a);                                           \
            float e0 = EXP2F(a[0]), e1 = EXP2F(a[1]);                          \
            float e2 = EXP2F(a[2]), e3 = EXP2F(a[3]);                          \
            psum += (e0 + e1) + (e2 + e3);                                     \
            bb.u[0] = pack2(e0, e1);                                           \
            bb.u[1] = pack2(e2, e3);                                           \
            f32x4 c = MFMA16(k10, bq0, breg1);                                 \
            c = MFMA16(k11, bq1, c);                                           \
            float f0 = EXP2F(c[0]), f1 = EXP2F(c[1]);                          \
            float f2 = EXP2F(c[2]), f3 = EXP2F(c[3]);                          \
            psum += (f0 + f1) + (f2 + f3);                                     \
            bb.u[2] = pack2(f0, f1);                                           \
            bb.u[3] = pack2(f2, f3);                                           \
        }                                                                      \
        if (DOBIAS) {                                                          \
            breg0 = *(const f32x4*)(bptr);                                     \
            breg1 = *(const f32x4*)(bptr + 16);                                \
            bptr += 32;                                                        \
        }                                                                      \
        acc_o[0] = MFMA16(vf0, bb.v, acc_o[0]);                                \
        acc_o[1] = MFMA16(vf1, bb.v, acc_o[1]);                                \
        acc_o[2] = MFMA16(vf2, bb.v, acc_o[2]);                                \
        acc_o[3] = MFMA16(vf3, bb.v, acc_o[3]);                                \
        if (DOSTAGE) STAGEK(kvw + bufsel)                                      \
        bufsel ^= 4096;                                                        \
    }

    BODY(4, true, true)                        // t = 0
    for (int t = 1; t < 14; ++t)
        BODY(6, true, true)                    // t = 1..13
    BODY(6, true, false)                       // t = 14 (bias_15, no stage)
    BODY(2, false, false)                      // t = 15

#undef BODY
#undef STAGEK

    // ---- split-K=8 merge: pure add (max-free softmax) ----
    __syncthreads();                           // staging LDS now dead
    float* mbuf = (float*)smem;                // 7 regions x 1024 fp32 (4 KB)
    float* lbuf = mbuf + 7 * 1024;             // 16 rows x 36 fp32 (padded)

    // all waves: psum -> lbuf[q][w*4+quad]
    lbuf[lm * 36 + w * 4 + quad] = psum;

    if (w != 0) {
        float* ob = mbuf + (w - 1) * 1024;     // 16 q x 64 d fp32, slot-swizzled
#pragma unroll
        for (int mt = 0; mt < 4; ++mt) {
            const int sl = (mt * 4 + quad) ^ lm;
            *(f32x4*)(ob + lm * 64 + sl * 4) = acc_o[mt];
        }
    }
    __syncthreads();
    if (w != 0) return;

    {
        f32x4 lv = (f32x4){0.f, 0.f, 0.f, 0.f};
#pragma unroll
        for (int j = 0; j < 8; ++j)
            lv += *(const f32x4*)(lbuf + lm * 36 + j * 4);
        const float inv = 1.0f / ((lv[0] + lv[1]) + (lv[2] + lv[3]));
#pragma unroll
        for (int mt = 0; mt < 4; ++mt) {
            const int sl = (mt * 4 + quad) ^ lm;
            f32x4 o = acc_o[mt];
#pragma unroll
            for (int p = 0; p < 7; ++p)
                o += *(const f32x4*)(mbuf + p * 1024 + lm * 64 + sl * 4);
            u16x4 pkv;
#pragma unroll
            for (int r2 = 0; r2 < 4; ++r2)
                pkv[r2] = f2bf(o[r2] * inv);
            *reinterpret_cast<u16x4*>(Ot + (size_t)(q0 + lm) * 512 +
                                      hq + mt * 16 + quad * 4) = pkv;
        }
    }
}

// ---------------------------------------------------------------------------
extern "C" void kernel_launch(void* const* d_in, const int* in_sizes, int n_in,
                              void* d_out, int out_size, void* d_ws, size_t ws_size,
                              hipStream_t stream) {
    (void)in_sizes; (void)n_in; (void)out_size; (void)ws_size;
    const float* X   = (const float*)d_in[0];
    const float* qw  = (const float*)d_in[1];
    const float* qb  = (const float*)d_in[2];
    const float* kw  = (const float*)d_in[3];
    const float* kb  = (const float*)d_in[4];
    const float* vw  = (const float*)d_in[5];
    const float* vb  = (const float*)d_in[6];
    const float* pw  = (const float*)d_in[7];
    const float* pb  = (const float*)d_in[8];
    const float* lqw = (const float*)d_in[9];

    const size_t E = (size_t)4096 * 512;
    const size_t WE = (size_t)512 * 512;
    u16* Xt    = (u16*)d_ws;
    u16* Qt    = Xt + E;
    u16* Kt    = Qt + E;
    u16* Vp    = Kt + E;
    u16* Wqkv  = Vp + E;          // 1536 x 512 stacked
    u16* Wp    = Wqkv + 3 * WE;
    float* lqw2g = (float*)(Wp + WE);   // 4096 fp32, 16B-aligned
    u16* Ot    = Xt;              // reuse (dead after qkv)

    prep<<<dim3(64, 13), dim3(256), 0, stream>>>(X, Xt, qw, kw, vw, pw,
                                                 Wqkv, Wp, lqw, lqw2g);
    qkv_gemm<<<dim3(32, 12), dim3(512), 0, stream>>>(Wqkv, Xt, qb, kb, vb, Qt, Kt, Vp);
    flash_attn<<<dim3(2048), dim3(512), 0, stream>>>(Qt, Kt, Vp, lqw2g, Ot);
    out_gemm<<<dim3(64, 4), dim3(256), 0, stream>>>(Wp, Ot, pb, (float*)d_out);
}

// Round 9
// 86.831 us; speedup vs baseline: 2.2688x; 2.2688x over previous
//
#include <hip/hip_runtime.h>

typedef unsigned short u16;
typedef unsigned int u32;
typedef __bf16 bf16x8 __attribute__((ext_vector_type(8)));
typedef float f32x4 __attribute__((ext_vector_type(4)));
typedef unsigned short u16x4 __attribute__((ext_vector_type(4)));

#define LOG2E 1.4426950408889634f

#if __has_builtin(__builtin_amdgcn_exp2f)
#define EXP2F(x) __builtin_amdgcn_exp2f(x)
#else
#define EXP2F(x) exp2f(x)
#endif

__device__ __forceinline__ u16 f2bf(float f) {
    union { float f; u32 u; } a; a.f = f;
    u32 u = a.u;
    u += 0x7FFFu + ((u >> 16) & 1u);   // RNE (finite inputs)
    return (u16)(u >> 16);
}
__device__ __forceinline__ bf16x8 ldg8(const u16* p) {
    return *reinterpret_cast<const bf16x8*>(p);
}
#if __has_builtin(__builtin_amdgcn_cvt_pk_bf16_f32)
__device__ __forceinline__ u32 pack2(float a, float b) {
    auto r = __builtin_amdgcn_cvt_pk_bf16_f32(a, b);   // v_cvt_pk_bf16_f32
    return __builtin_bit_cast(u32, r);
}
#else
__device__ __forceinline__ u32 pack2(float a, float b) {
    u32 ua = __float_as_uint(a) + 0x8000u;
    u32 ub = __float_as_uint(b) + 0x8000u;
    return __builtin_amdgcn_perm(ub, ua, 0x07060302);
}
#endif
// async global -> LDS, 16 B per lane. LDS dest = wave-uniform base + lane*16.
__device__ __forceinline__ void async16(const void* g, void* l) {
    __builtin_amdgcn_global_load_lds(
        (const __attribute__((address_space(1))) u32*)g,
        (__attribute__((address_space(3))) u32*)l, 16, 0, 0);
}

#define MFMA16(a, b, c) __builtin_amdgcn_mfma_f32_16x16x32_bf16((a), (b), (c), 0, 0, 0)

// ---------------------------------------------------------------------------
// Fused prep: y<8 -> transpose X tile; y in 8..11 -> pack weight matrix;
// y==12 -> lqw * log2(e) into global fp32 (4 blocks). Grid (64, 13).
// ---------------------------------------------------------------------------
__global__ __launch_bounds__(256) void prep(const float* __restrict__ X,
                                            u16* __restrict__ Xt,
                                            const float* __restrict__ s0,
                                            const float* __restrict__ s1,
                                            const float* __restrict__ s2,
                                            const float* __restrict__ s3,
                                            u16* __restrict__ Wqkv,
                                            u16* __restrict__ Wp,
                                            const float* __restrict__ lqw,
                                            float* __restrict__ lqw2g) {
    __shared__ u16 tile[64][65];
    const int tid = threadIdx.x;
    const int y = blockIdx.y;

    if (y < 8) {                                  // transpose 64x64 tile
        const int t0 = blockIdx.x * 64;
        const int c0 = y * 64;
#pragma unroll
        for (int i = 0; i < 16; ++i) {
            int idx = tid + i * 256;
            int r = idx >> 6, cc = idx & 63;
            tile[r][cc] = f2bf(X[(size_t)(c0 + r) * 4096 + t0 + cc]);
        }
        __syncthreads();
#pragma unroll
        for (int i = 0; i < 16; ++i) {
            int idx = tid + i * 256;
            int tr = idx >> 6, cc = idx & 63;
            Xt[(size_t)(t0 + tr) * 512 + c0 + cc] = tile[cc][tr];
        }
    } else if (y < 12) {                          // pack one 512x512 weight
        const int m = y - 8;
        const float* s = (m == 0) ? s0 : (m == 1) ? s1 : (m == 2) ? s2 : s3;
        u16* d = (m == 3) ? Wp : Wqkv + (size_t)m * 262144;
#pragma unroll
        for (int j = 0; j < 4; ++j) {
            int i = blockIdx.x * 1024 + j * 256 + tid;
            float4 v = reinterpret_cast<const float4*>(s)[i];
            u16x4 o;
            o[0] = f2bf(v.x); o[1] = f2bf(v.y); o[2] = f2bf(v.z); o[3] = f2bf(v.w);
            reinterpret_cast<u16x4*>(d)[i] = o;
        }
    } else {                                      // lqw * LOG2E (1024 float4)
        if (blockIdx.x < 4) {
            int i = blockIdx.x * 256 + tid;
            float4 v = reinterpret_cast<const float4*>(lqw)[i];
            v.x *= LOG2E; v.y *= LOG2E; v.z *= LOG2E; v.w *= LOG2E;
            reinterpret_cast<float4*>(lqw2g)[i] = v;
        }
    }
}

// ---------------------------------------------------------------------------
// Fused QKV GEMM, LDS-staged (unchanged, known-good).
// ---------------------------------------------------------------------------
__global__ __launch_bounds__(512, 2) void qkv_gemm(const u16* __restrict__ Wqkv,
                                                   const u16* __restrict__ Xt,
                                                   const float* __restrict__ qb,
                                                   const float* __restrict__ kb,
                                                   const float* __restrict__ vb,
                                                   u16* __restrict__ Qt,
                                                   u16* __restrict__ Kt,
                                                   u16* __restrict__ Vp) {
    __shared__ __align__(16) u16 Al[2][128 * 32];
    __shared__ __align__(16) u16 Bl[2][128 * 32];

    const int tid = threadIdx.x;
    const int w = tid >> 6, lane = tid & 63;
    const int quad = lane >> 4, lm = lane & 15;
    const int wm = w & 1, wn = w >> 1;
    const int n0 = blockIdx.x * 128;
    const int my = blockIdx.y;
    const int m0 = my * 128;

    const int arow = lane >> 2;
    const int sch = (lane & 3) ^ ((lane >> 3) & 3);   // source chunk (XOR on row>>1)
    const u16* agp = Wqkv + (size_t)(m0 + w * 16 + arow) * 512 + sch * 8;
    const u16* bgp = Xt + (size_t)(n0 + w * 16 + arow) * 512 + sch * 8;

    async16(agp, &Al[0][w * 16 * 32]);
    async16(bgp, &Bl[0][w * 16 * 32]);
    agp += 32; bgp += 32;

    const int FOFF = lm * 64 + ((quad ^ ((lm >> 1) & 3)) << 4);

    f32x4 acc[4][2];
#pragma unroll
    for (int mt = 0; mt < 4; ++mt)
#pragma unroll
        for (int bt = 0; bt < 2; ++bt) acc[mt][bt] = (f32x4){0.f, 0.f, 0.f, 0.f};

    __syncthreads();

    for (int s = 0; s < 16; ++s) {
        const int buf = s & 1;
        if (s < 15) {
            async16(agp, &Al[buf ^ 1][w * 16 * 32]);
            async16(bgp, &Bl[buf ^ 1][w * 16 * 32]);
            agp += 32; bgp += 32;
        }
        const char* Ab = (const char*)&Al[buf][0];
        const char* Bb = (const char*)&Bl[buf][0];
        bf16x8 af[4], bfr[2];
#pragma unroll
        for (int mt = 0; mt < 4; ++mt)
            af[mt] = *(const bf16x8*)(Ab + wm * 4096 + mt * 1024 + FOFF);
#pragma unroll
        for (int bt = 0; bt < 2; ++bt)
            bfr[bt] = *(const bf16x8*)(Bb + wn * 2048 + bt * 1024 + FOFF);
#pragma unroll
        for (int mt = 0; mt < 4; ++mt)
#pragma unroll
            for (int bt = 0; bt < 2; ++bt)
                acc[mt][bt] = MFMA16(af[mt], bfr[bt], acc[mt][bt]);
        __syncthreads();
    }

    const int mat = my >> 2;                     // 0=Q, 1=K, 2=V
    const float* bias = (mat == 0) ? qb : (mat == 1) ? kb : vb;
    const int chbase = (my & 3) * 128 + wm * 64 + quad * 4;

    if (mat < 2) {
        u16* out = mat ? Kt : Qt;
        const float sc = mat ? 1.0f : 0.125f * LOG2E;
#pragma unroll
        for (int mt = 0; mt < 4; ++mt) {
            const int ch = chbase + mt * 16;
            float4 bv = *(const float4*)(bias + ch);
            float bvf[4] = {bv.x, bv.y, bv.z, bv.w};
#pragma unroll
            for (int bt = 0; bt < 2; ++bt) {
                int tok = n0 + wn * 32 + bt * 16 + lm;
                u16x4 pk;
#pragma unroll
                for (int r = 0; r < 4; ++r)
                    pk[r] = f2bf((acc[mt][bt][r] + bvf[r]) * sc);
                *(u16x4*)(out + (size_t)tok * 512 + ch) = pk;
            }
        }
    } else {
#pragma unroll
        for (int mt = 0; mt < 4; ++mt) {
            const int ch = chbase + mt * 16;
            float4 bv = *(const float4*)(bias + ch);
            float bvf[4] = {bv.x, bv.y, bv.z, bv.w};
#pragma unroll
            for (int bt = 0; bt < 2; ++bt) {
                int g = bt * 16 + lm;
                int col = n0 + wn * 32 + 8 * ((g >> 2) & 3) + 4 * ((g >> 4) & 1) + (g & 3);
#pragma unroll
                for (int r = 0; r < 4; ++r)
                    Vp[(size_t)(ch + r) * 4096 + col] = f2bf(acc[mt][bt][r] + bvf[r]);
            }
        }
    }
}

// ---------------------------------------------------------------------------
// Output projection, LDS-staged (unchanged, known-good).
// ---------------------------------------------------------------------------
__global__ __launch_bounds__(256, 2) void out_gemm(const u16* __restrict__ Wp,
                                                   const u16* __restrict__ Ot,
                                                   const float* __restrict__ pb,
                                                   float* __restrict__ out) {
    __shared__ __align__(16) u16 Al[2][128 * 32];
    __shared__ __align__(16) u16 Bl[2][64 * 32];

    const int tid = threadIdx.x;
    const int w = tid >> 6, lane = tid & 63;
    const int quad = lane >> 4, lm = lane & 15;
    const int wm = w & 1, wn = w >> 1;
    const int n0 = blockIdx.x * 64;
    const int m0 = blockIdx.y * 128;

    const int arow = lane >> 2;
    const int sch = (lane & 3) ^ ((lane >> 3) & 3);
    const u16* agp0 = Wp + (size_t)(m0 + w * 16 + arow) * 512 + sch * 8;
    const u16* agp1 = agp0 + (size_t)64 * 512;
    const u16* bgp = Ot + (size_t)(n0 + w * 16 + arow) * 512 + sch * 8;

    async16(agp0, &Al[0][w * 16 * 32]);
    async16(agp1, &Al[0][(64 + w * 16) * 32]);
    async16(bgp, &Bl[0][w * 16 * 32]);
    agp0 += 32; agp1 += 32; bgp += 32;

    const int FOFF = lm * 64 + ((quad ^ ((lm >> 1) & 3)) << 4);

    f32x4 acc[4][2];
#pragma unroll
    for (int mt = 0; mt < 4; ++mt)
#pragma unroll
        for (int bt = 0; bt < 2; ++bt) acc[mt][bt] = (f32x4){0.f, 0.f, 0.f, 0.f};

    __syncthreads();

    for (int s = 0; s < 16; ++s) {
        const int buf = s & 1;
        if (s < 15) {
            async16(agp0, &Al[buf ^ 1][w * 16 * 32]);
            async16(agp1, &Al[buf ^ 1][(64 + w * 16) * 32]);
            async16(bgp, &Bl[buf ^ 1][w * 16 * 32]);
            agp0 += 32; agp1 += 32; bgp += 32;
        }
        const char* Ab = (const char*)&Al[buf][0];
        const char* Bb = (const char*)&Bl[buf][0];
        bf16x8 af[4], bfr[2];
#pragma unroll
        for (int mt = 0; mt < 4; ++mt)
            af[mt] = *(const bf16x8*)(Ab + wm * 4096 + mt * 1024 + FOFF);
#pragma unroll
        for (int bt = 0; bt < 2; ++bt)
            bfr[bt] = *(const bf16x8*)(Bb + wn * 2048 + bt * 1024 + FOFF);
#pragma unroll
        for (int mt = 0; mt < 4; ++mt)
#pragma unroll
            for (int bt = 0; bt < 2; ++bt)
                acc[mt][bt] = MFMA16(af[mt], bfr[bt], acc[mt][bt]);
        __syncthreads();
    }

#pragma unroll
    for (int mt = 0; mt < 4; ++mt) {
        const int ch = m0 + wm * 64 + mt * 16 + quad * 4;
        float4 bv = *(const float4*)(pb + ch);
        float bvf[4] = {bv.x, bv.y, bv.z, bv.w};
#pragma unroll
        for (int bt = 0; bt < 2; ++bt) {
            int tok = n0 + wn * 32 + bt * 16 + lm;
#pragma unroll
            for (int r = 0; r < 4; ++r)
                out[(size_t)(ch + r) * 4096 + tok] = acc[mt][bt][r] + bvf[r];
        }
    }
}

// ---------------------------------------------------------------------------
// Flash attention v8: q_block=128, SHARED K/V LDS staging, counted-vmcnt
// raw barriers (no drain). R8 post-mortem: no-spill v7 got WORSE (176 us);
// all rounds since R3 fit an L2-traffic model: traffic = #blocks/head x
// K+V/head at effective ~11.6 TB/s (R3 512MB->48us, v6 1GB->104, v7
// 2GB->176). The kernel is L2-BANDWIDTH-bound, not latency-bound.
// v8 cuts traffic 2x vs R3: 256 blocks (32 q-grp x 8 heads, 1/CU),
// 8 waves = 4 key-quarters x 2 q-halves; each 32-key K/V tile staged ONCE
// (qh0 stages K 4KB, qh1 stages V 4KB) and consumed by 2 waves x 4
// q-subtiles -> 256 MB total, plus staging makes V reads coalesced 1KB.
// Per wave: 64 q x 1024 keys; acc 64 AGPR + Q 32 VGPR ~ 195 regs, cap 256
// (launch_bounds(512,2)) -> no spill, margin ~60.
// Sync per step (no __syncthreads drain, m201 idiom): issue stage_{t+1} +
// bias_{t+1} -> s_waitcnt vmcnt(6) (retires stage_t, leaves 6 in flight)
// -> s_barrier (tile t complete block-wide) -> sched_barrier(0) ->
// ds_read K/V frags, QK MFMA(bias C-init), exp2, pack, PV MFMA ->
// s_barrier (all done reading buf before overwrite) -> sched_barrier(0).
// Last step vmcnt(2). LDS: 4 kq x 2 buf x (K 4KB|V 4KB) = 64 KB.
// Merge: split-K=4, two d-half phases through dead staging LDS (48 KB
// regions + 10 KB lbuf), slot-swizzled, 3 __syncthreads.
// Fragment layouts (A0/A1, AV, Vp column permutation, bb pack) carried
// verbatim from R1/R3-proven kernels.
// ---------------------------------------------------------------------------
#define WAITVM(N) asm volatile("s_waitcnt vmcnt(" #N ")" ::: "memory")
#define SBAR() __builtin_amdgcn_s_barrier()
#define SCHEDB() __builtin_amdgcn_sched_barrier(0)

__global__ __launch_bounds__(512, 2) void flash_attn(const u16* __restrict__ Qt,
                                                     const u16* __restrict__ Kt,
                                                     const u16* __restrict__ Vp,
                                                     const float* __restrict__ lqw2g,
                                                     u16* __restrict__ Ot) {
    __shared__ __align__(16) char smem[65536];

    const int tid = threadIdx.x;
    const int w = tid >> 6, lane = tid & 63;         // 8 waves
    const int quad = lane >> 4, lm = lane & 15;
    const int qh = w & 1, kq = w >> 1;               // q-half, key-quarter
    const int bid = blockIdx.x;
    const int h = bid & 7, hq = h * 64;              // head -> XCD cluster
    const int q0 = (bid >> 3) * 128;
    const int kstart = kq * 1024;

    char* kvb = smem + kq * 16384;                   // [buf 8KB][K 4KB | V 4KB]

    // staging lane addressing (XOR swizzle at global source, LDS linear)
    const int srow = lane >> 3;                      // 0..7
    const int schunk = (lane & 7) ^ srow;
    const u16* kg = Kt + (size_t)(kstart + srow) * 512 + hq + schunk * 8;
    const u16* vg = Vp + (size_t)(hq + 2 * srow + (schunk >> 2)) * 4096 +
                    kstart + (schunk & 3) * 8;

    // Q fragments: 4 subtiles (this wave's 64 q) x 2 d-halves
    bf16x8 bq0[4], bq1[4];
#pragma unroll
    for (int s = 0; s < 4; ++s) {
        const u16* qb = Qt + (size_t)(q0 + qh * 64 + s * 16 + lm) * 512 + hq + quad * 8;
        bq0[s] = ldg8(qb);
        bq1[s] = ldg8(qb + 32);
    }

    // bias prefetch registers
    f32x4 breg0 = *(const f32x4*)(lqw2g + kstart + quad * 4);
    f32x4 breg1 = *(const f32x4*)(lqw2g + kstart + 16 + quad * 4);
    const float* bptr = lqw2g + kstart + 32 + quad * 4;

    // fragment read offsets (proven layouts)
    const int A0 = lm * 128 + ((quad ^ (lm & 7)) << 4);       // K, d 0..31
    const int A1 = A0 ^ 64;                                   // K, d 32..63
    const int AV = (lm >> 1) * 128 +
                   (((4 * (lm & 1) + quad) ^ ((lm >> 1) & 7)) << 4);  // V pair-row

    // qh0 stages K (4 x 1KB), qh1 stages V (4 x 1KB) — 4 async16 per wave
#define STAGE(DST)                                                             \
    {                                                                          \
        char* nb = (DST);                                                      \
        if (qh == 0) {                                                         \
            async16(kg, nb);                                                   \
            async16(kg + 8 * 512, nb + 1024);                                  \
            async16(kg + 16 * 512, nb + 2048);                                 \
            async16(kg + 24 * 512, nb + 3072);                                 \
            kg += 32 * 512;                                                    \
        } else {                                                               \
            async16(vg, nb + 4096);                                            \
            async16(vg + (size_t)16 * 4096, nb + 5120);                        \
            async16(vg + (size_t)32 * 4096, nb + 6144);                        \
            async16(vg + (size_t)48 * 4096, nb + 7168);                        \
            vg += 32;                                                          \
        }                                                                      \
    }

    STAGE(kvb)                                        // tile 0 -> buf0

    f32x4 acc_o[4][4];                                // [d-group][q-sub]
#pragma unroll
    for (int mt = 0; mt < 4; ++mt)
#pragma unroll
        for (int s = 0; s < 4; ++s) acc_o[mt][s] = (f32x4){0.f, 0.f, 0.f, 0.f};
    float psum[4] = {0.f, 0.f, 0.f, 0.f};

    int bufsel = 0;

#define BODY(WN, DO)                                                           \
    {                                                                          \
        f32x4 bnext0, bnext1;                                                  \
        if (DO) {                                                              \
            STAGE(kvb + (bufsel ^ 8192))                                       \
            bnext0 = *(const f32x4*)(bptr);                                    \
            bnext1 = *(const f32x4*)(bptr + 16);                               \
            bptr += 32;                                                        \
        }                                                                      \
        WAITVM(WN);                                                            \
        SBAR();                                                                \
        SCHEDB();                                                              \
        const char* Kb = kvb + bufsel;                                         \
        const char* Vb = Kb + 4096;                                            \
        bf16x8 k00 = *(const bf16x8*)(Kb + A0);                                \
        bf16x8 k01 = *(const bf16x8*)(Kb + A1);                                \
        bf16x8 k10 = *(const bf16x8*)(Kb + 2048 + A0);                         \
        bf16x8 k11 = *(const bf16x8*)(Kb + 2048 + A1);                         \
        bf16x8 vf0 = *(const bf16x8*)(Vb + AV);                                \
        bf16x8 vf1 = *(const bf16x8*)(Vb + 1024 + AV);                         \
        bf16x8 vf2 = *(const bf16x8*)(Vb + 2048 + AV);                         \
        bf16x8 vf3 = *(const bf16x8*)(Vb + 3072 + AV);                         \
        union { u32 u[4]; bf16x8 v; } bb[4];                                   \
        _Pragma("unroll")                                                      \
        for (int s = 0; s < 4; ++s) {                                          \
            f32x4 a = MFMA16(k00, bq0[s], breg0);                              \
            a = MFMA16(k01, bq1[s], a);                                        \
            float e0 = EXP2F(a[0]), e1 = EXP2F(a[1]);                          \
            float e2 = EXP2F(a[2]), e3 = EXP2F(a[3]);                          \
            psum[s] += (e0 + e1) + (e2 + e3);                                  \
            bb[s].u[0] = pack2(e0, e1);                                        \
            bb[s].u[1] = pack2(e2, e3);                                        \
            f32x4 c = MFMA16(k10, bq0[s], breg1);                              \
            c = MFMA16(k11, bq1[s], c);                                        \
            float f0 = EXP2F(c[0]), f1 = EXP2F(c[1]);                          \
            float f2 = EXP2F(c[2]), f3 = EXP2F(c[3]);                          \
            psum[s] += (f0 + f1) + (f2 + f3);                                  \
            bb[s].u[2] = pack2(f0, f1);                                        \
            bb[s].u[3] = pack2(f2, f3);                                        \
        }                                                                      \
        _Pragma("unroll")                                                      \
        for (int s = 0; s < 4; ++s) {                                          \
            acc_o[0][s] = MFMA16(vf0, bb[s].v, acc_o[0][s]);                   \
            acc_o[1][s] = MFMA16(vf1, bb[s].v, acc_o[1][s]);                   \
            acc_o[2][s] = MFMA16(vf2, bb[s].v, acc_o[2][s]);                   \
            acc_o[3][s] = MFMA16(vf3, bb[s].v, acc_o[3][s]);                   \
        }                                                                      \
        SBAR();                                                                \
        SCHEDB();                                                              \
        if (DO) { breg0 = bnext0; breg1 = bnext1; }                            \
        bufsel ^= 8192;                                                        \
    }

    for (int t = 0; t < 31; ++t)
        BODY(6, true)                          // steady: stage_{t+1}(4)+bias(2) in flight
    BODY(2, false)                             // t = 31

#undef BODY
#undef STAGE

    // ---- split-K=4 merge: pure add (max-free softmax), two d-half phases ----
    float* mbuf = (float*)smem;                // 3 regions x 4096 fp32 (16 KB each)
    float* lbuf = mbuf + 3 * 4096;             // 128 rows x 20 fp32 (padded)

    // psum -> lbuf[row][kq*4+quad] (all waves)
#pragma unroll
    for (int s = 0; s < 4; ++s)
        lbuf[(qh * 64 + s * 16 + lm) * 20 + kq * 4 + quad] = psum[s];

    // phase A: d 0..31 (mt 0,1)
    if (kq != 0) {
        float* ob = mbuf + (kq - 1) * 4096;
#pragma unroll
        for (int s = 0; s < 4; ++s) {
            const int row = qh * 64 + s * 16 + lm;
#pragma unroll
            for (int mt = 0; mt < 2; ++mt) {
                const int sl = (mt * 4 + quad) ^ (lm & 7);
                *(f32x4*)(ob + row * 32 + sl * 4) = acc_o[mt][s];
            }
        }
    }
    __syncthreads();
    float invs[4];
    if (kq == 0) {
#pragma unroll
        for (int s = 0; s < 4; ++s) {
            const int row = qh * 64 + s * 16 + lm;
            f32x4 lv = (f32x4){0.f, 0.f, 0.f, 0.f};
#pragma unroll
            for (int j = 0; j < 4; ++j)
                lv += *(const f32x4*)(lbuf + row * 20 + j * 4);
            invs[s] = 1.0f / ((lv[0] + lv[1]) + (lv[2] + lv[3]));
#pragma unroll
            for (int mt = 0; mt < 2; ++mt) {
                const int sl = (mt * 4 + quad) ^ (lm & 7);
                f32x4 o = acc_o[mt][s];
#pragma unroll
                for (int p = 0; p < 3; ++p)
                    o += *(const f32x4*)(mbuf + p * 4096 + row * 32 + sl * 4);
                u16x4 pkv;
#pragma unroll
                for (int r = 0; r < 4; ++r)
                    pkv[r] = f2bf(o[r] * invs[s]);
                *reinterpret_cast<u16x4*>(Ot + (size_t)(q0 + row) * 512 +
                                          hq + mt * 16 + quad * 4) = pkv;
            }
        }
    }
    __syncthreads();
    // phase B: d 32..63 (mt 2,3)
    if (kq != 0) {
        float* ob = mbuf + (kq - 1) * 4096;
#pragma unroll
        for (int s = 0; s < 4; ++s) {
            const int row = qh * 64 + s * 16 + lm;
#pragma unroll
            for (int mt = 2; mt < 4; ++mt) {
                const int sl = ((mt - 2) * 4 + quad) ^ (lm & 7);
                *(f32x4*)(ob + row * 32 + sl * 4) = acc_o[mt][s];
            }
        }
    }
    __syncthreads();
    if (kq != 0) return;

#pragma unroll
    for (int s = 0; s < 4; ++s) {
        const int row = qh * 64 + s * 16 + lm;
#pragma unroll
        for (int mt = 2; mt < 4; ++mt) {
            const int sl = ((mt - 2) * 4 + quad) ^ (lm & 7);
            f32x4 o = acc_o[mt][s];
#pragma unroll
            for (int p = 0; p < 3; ++p)
                o += *(const f32x4*)(mbuf + p * 4096 + row * 32 + sl * 4);
            u16x4 pkv;
#pragma unroll
            for (int r = 0; r < 4; ++r)
                pkv[r] = f2bf(o[r] * invs[s]);
            *reinterpret_cast<u16x4*>(Ot + (size_t)(q0 + row) * 512 +
                                      hq + mt * 16 + quad * 4) = pkv;
        }
    }
}

// ---------------------------------------------------------------------------
extern "C" void kernel_launch(void* const* d_in, const int* in_sizes, int n_in,
                              void* d_out, int out_size, void* d_ws, size_t ws_size,
                              hipStream_t stream) {
    (void)in_sizes; (void)n_in; (void)out_size; (void)ws_size;
    const float* X   = (const float*)d_in[0];
    const float* qw  = (const float*)d_in[1];
    const float* qb  = (const float*)d_in[2];
    const float* kw  = (const float*)d_in[3];
    const float* kb  = (const float*)d_in[4];
    const float* vw  = (const float*)d_in[5];
    const float* vb  = (const float*)d_in[6];
    const float* pw  = (const float*)d_in[7];
    const float* pb  = (const float*)d_in[8];
    const float* lqw = (const float*)d_in[9];

    const size_t E = (size_t)4096 * 512;
    const size_t WE = (size_t)512 * 512;
    u16* Xt    = (u16*)d_ws;
    u16* Qt    = Xt + E;
    u16* Kt    = Qt + E;
    u16* Vp    = Kt + E;
    u16* Wqkv  = Vp + E;          // 1536 x 512 stacked
    u16* Wp    = Wqkv + 3 * WE;
    float* lqw2g = (float*)(Wp + WE);   // 4096 fp32, 16B-aligned
    u16* Ot    = Xt;              // reuse (dead after qkv)

    prep<<<dim3(64, 13), dim3(256), 0, stream>>>(X, Xt, qw, kw, vw, pw,
                                                 Wqkv, Wp, lqw, lqw2g);
    qkv_gemm<<<dim3(32, 12), dim3(512), 0, stream>>>(Wqkv, Xt, qb, kb, vb, Qt, Kt, Vp);
    flash_attn<<<dim3(256), dim3(512), 0, stream>>>(Qt, Kt, Vp, lqw2g, Ot);
    out_gemm<<<dim3(64, 4), dim3(256), 0, stream>>>(Wp, Ot, pb, (float*)d_out);
}

// Round 10
// 77.745 us; speedup vs baseline: 2.5340x; 1.1169x over previous
//
#include <hip/hip_runtime.h>

typedef unsigned short u16;
typedef unsigned int u32;
typedef __bf16 bf16x8 __attribute__((ext_vector_type(8)));
typedef float f32x4 __attribute__((ext_vector_type(4)));
typedef unsigned short u16x4 __attribute__((ext_vector_type(4)));

#define LOG2E 1.4426950408889634f

#if __has_builtin(__builtin_amdgcn_exp2f)
#define EXP2F(x) __builtin_amdgcn_exp2f(x)
#else
#define EXP2F(x) exp2f(x)
#endif

__device__ __forceinline__ u16 f2bf(float f) {
    union { float f; u32 u; } a; a.f = f;
    u32 u = a.u;
    u += 0x7FFFu + ((u >> 16) & 1u);   // RNE (finite inputs)
    return (u16)(u >> 16);
}
__device__ __forceinline__ bf16x8 ldg8(const u16* p) {
    return *reinterpret_cast<const bf16x8*>(p);
}
#if __has_builtin(__builtin_amdgcn_cvt_pk_bf16_f32)
__device__ __forceinline__ u32 pack2(float a, float b) {
    auto r = __builtin_amdgcn_cvt_pk_bf16_f32(a, b);   // v_cvt_pk_bf16_f32
    return __builtin_bit_cast(u32, r);
}
#else
__device__ __forceinline__ u32 pack2(float a, float b) {
    u32 ua = __float_as_uint(a) + 0x8000u;
    u32 ub = __float_as_uint(b) + 0x8000u;
    return __builtin_amdgcn_perm(ub, ua, 0x07060302);
}
#endif
// async global -> LDS, 16 B per lane. LDS dest = wave-uniform base + lane*16.
__device__ __forceinline__ void async16(const void* g, void* l) {
    __builtin_amdgcn_global_load_lds(
        (const __attribute__((address_space(1))) u32*)g,
        (__attribute__((address_space(3))) u32*)l, 16, 0, 0);
}

#define MFMA16(a, b, c) __builtin_amdgcn_mfma_f32_16x16x32_bf16((a), (b), (c), 0, 0, 0)

// ---------------------------------------------------------------------------
// Fused prep: y<8 -> transpose X tile; y in 8..11 -> pack weight matrix;
// y==12 -> lqw * log2(e) into global fp32 (4 blocks). Grid (64, 13).
// ---------------------------------------------------------------------------
__global__ __launch_bounds__(256) void prep(const float* __restrict__ X,
                                            u16* __restrict__ Xt,
                                            const float* __restrict__ s0,
                                            const float* __restrict__ s1,
                                            const float* __restrict__ s2,
                                            const float* __restrict__ s3,
                                            u16* __restrict__ Wqkv,
                                            u16* __restrict__ Wp,
                                            const float* __restrict__ lqw,
                                            float* __restrict__ lqw2g) {
    __shared__ u16 tile[64][65];
    const int tid = threadIdx.x;
    const int y = blockIdx.y;

    if (y < 8) {                                  // transpose 64x64 tile
        const int t0 = blockIdx.x * 64;
        const int c0 = y * 64;
#pragma unroll
        for (int i = 0; i < 16; ++i) {
            int idx = tid + i * 256;
            int r = idx >> 6, cc = idx & 63;
            tile[r][cc] = f2bf(X[(size_t)(c0 + r) * 4096 + t0 + cc]);
        }
        __syncthreads();
#pragma unroll
        for (int i = 0; i < 16; ++i) {
            int idx = tid + i * 256;
            int tr = idx >> 6, cc = idx & 63;
            Xt[(size_t)(t0 + tr) * 512 + c0 + cc] = tile[cc][tr];
        }
    } else if (y < 12) {                          // pack one 512x512 weight
        const int m = y - 8;
        const float* s = (m == 0) ? s0 : (m == 1) ? s1 : (m == 2) ? s2 : s3;
        u16* d = (m == 3) ? Wp : Wqkv + (size_t)m * 262144;
#pragma unroll
        for (int j = 0; j < 4; ++j) {
            int i = blockIdx.x * 1024 + j * 256 + tid;
            float4 v = reinterpret_cast<const float4*>(s)[i];
            u16x4 o;
            o[0] = f2bf(v.x); o[1] = f2bf(v.y); o[2] = f2bf(v.z); o[3] = f2bf(v.w);
            reinterpret_cast<u16x4*>(d)[i] = o;
        }
    } else {                                      // lqw * LOG2E (1024 float4)
        if (blockIdx.x < 4) {
            int i = blockIdx.x * 256 + tid;
            float4 v = reinterpret_cast<const float4*>(lqw)[i];
            v.x *= LOG2E; v.y *= LOG2E; v.z *= LOG2E; v.w *= LOG2E;
            reinterpret_cast<float4*>(lqw2g)[i] = v;
        }
    }
}

// ---------------------------------------------------------------------------
// Fused QKV GEMM, LDS-staged (unchanged, known-good).
// ---------------------------------------------------------------------------
__global__ __launch_bounds__(512, 2) void qkv_gemm(const u16* __restrict__ Wqkv,
                                                   const u16* __restrict__ Xt,
                                                   const float* __restrict__ qb,
                                                   const float* __restrict__ kb,
                                                   const float* __restrict__ vb,
                                                   u16* __restrict__ Qt,
                                                   u16* __restrict__ Kt,
                                                   u16* __restrict__ Vp) {
    __shared__ __align__(16) u16 Al[2][128 * 32];
    __shared__ __align__(16) u16 Bl[2][128 * 32];

    const int tid = threadIdx.x;
    const int w = tid >> 6, lane = tid & 63;
    const int quad = lane >> 4, lm = lane & 15;
    const int wm = w & 1, wn = w >> 1;
    const int n0 = blockIdx.x * 128;
    const int my = blockIdx.y;
    const int m0 = my * 128;

    const int arow = lane >> 2;
    const int sch = (lane & 3) ^ ((lane >> 3) & 3);   // source chunk (XOR on row>>1)
    const u16* agp = Wqkv + (size_t)(m0 + w * 16 + arow) * 512 + sch * 8;
    const u16* bgp = Xt + (size_t)(n0 + w * 16 + arow) * 512 + sch * 8;

    async16(agp, &Al[0][w * 16 * 32]);
    async16(bgp, &Bl[0][w * 16 * 32]);
    agp += 32; bgp += 32;

    const int FOFF = lm * 64 + ((quad ^ ((lm >> 1) & 3)) << 4);

    f32x4 acc[4][2];
#pragma unroll
    for (int mt = 0; mt < 4; ++mt)
#pragma unroll
        for (int bt = 0; bt < 2; ++bt) acc[mt][bt] = (f32x4){0.f, 0.f, 0.f, 0.f};

    __syncthreads();

    for (int s = 0; s < 16; ++s) {
        const int buf = s & 1;
        if (s < 15) {
            async16(agp, &Al[buf ^ 1][w * 16 * 32]);
            async16(bgp, &Bl[buf ^ 1][w * 16 * 32]);
            agp += 32; bgp += 32;
        }
        const char* Ab = (const char*)&Al[buf][0];
        const char* Bb = (const char*)&Bl[buf][0];
        bf16x8 af[4], bfr[2];
#pragma unroll
        for (int mt = 0; mt < 4; ++mt)
            af[mt] = *(const bf16x8*)(Ab + wm * 4096 + mt * 1024 + FOFF);
#pragma unroll
        for (int bt = 0; bt < 2; ++bt)
            bfr[bt] = *(const bf16x8*)(Bb + wn * 2048 + bt * 1024 + FOFF);
#pragma unroll
        for (int mt = 0; mt < 4; ++mt)
#pragma unroll
            for (int bt = 0; bt < 2; ++bt)
                acc[mt][bt] = MFMA16(af[mt], bfr[bt], acc[mt][bt]);
        __syncthreads();
    }

    const int mat = my >> 2;                     // 0=Q, 1=K, 2=V
    const float* bias = (mat == 0) ? qb : (mat == 1) ? kb : vb;
    const int chbase = (my & 3) * 128 + wm * 64 + quad * 4;

    if (mat < 2) {
        u16* out = mat ? Kt : Qt;
        const float sc = mat ? 1.0f : 0.125f * LOG2E;
#pragma unroll
        for (int mt = 0; mt < 4; ++mt) {
            const int ch = chbase + mt * 16;
            float4 bv = *(const float4*)(bias + ch);
            float bvf[4] = {bv.x, bv.y, bv.z, bv.w};
#pragma unroll
            for (int bt = 0; bt < 2; ++bt) {
                int tok = n0 + wn * 32 + bt * 16 + lm;
                u16x4 pk;
#pragma unroll
                for (int r = 0; r < 4; ++r)
                    pk[r] = f2bf((acc[mt][bt][r] + bvf[r]) * sc);
                *(u16x4*)(out + (size_t)tok * 512 + ch) = pk;
            }
        }
    } else {
#pragma unroll
        for (int mt = 0; mt < 4; ++mt) {
            const int ch = chbase + mt * 16;
            float4 bv = *(const float4*)(bias + ch);
            float bvf[4] = {bv.x, bv.y, bv.z, bv.w};
#pragma unroll
            for (int bt = 0; bt < 2; ++bt) {
                int g = bt * 16 + lm;
                int col = n0 + wn * 32 + 8 * ((g >> 2) & 3) + 4 * ((g >> 4) & 1) + (g & 3);
#pragma unroll
                for (int r = 0; r < 4; ++r)
                    Vp[(size_t)(ch + r) * 4096 + col] = f2bf(acc[mt][bt][r] + bvf[r]);
            }
        }
    }
}

// ---------------------------------------------------------------------------
// Output projection, LDS-staged (unchanged, known-good).
// ---------------------------------------------------------------------------
__global__ __launch_bounds__(256, 2) void out_gemm(const u16* __restrict__ Wp,
                                                   const u16* __restrict__ Ot,
                                                   const float* __restrict__ pb,
                                                   float* __restrict__ out) {
    __shared__ __align__(16) u16 Al[2][128 * 32];
    __shared__ __align__(16) u16 Bl[2][64 * 32];

    const int tid = threadIdx.x;
    const int w = tid >> 6, lane = tid & 63;
    const int quad = lane >> 4, lm = lane & 15;
    const int wm = w & 1, wn = w >> 1;
    const int n0 = blockIdx.x * 64;
    const int m0 = blockIdx.y * 128;

    const int arow = lane >> 2;
    const int sch = (lane & 3) ^ ((lane >> 3) & 3);
    const u16* agp0 = Wp + (size_t)(m0 + w * 16 + arow) * 512 + sch * 8;
    const u16* agp1 = agp0 + (size_t)64 * 512;
    const u16* bgp = Ot + (size_t)(n0 + w * 16 + arow) * 512 + sch * 8;

    async16(agp0, &Al[0][w * 16 * 32]);
    async16(agp1, &Al[0][(64 + w * 16) * 32]);
    async16(bgp, &Bl[0][w * 16 * 32]);
    agp0 += 32; agp1 += 32; bgp += 32;

    const int FOFF = lm * 64 + ((quad ^ ((lm >> 1) & 3)) << 4);

    f32x4 acc[4][2];
#pragma unroll
    for (int mt = 0; mt < 4; ++mt)
#pragma unroll
        for (int bt = 0; bt < 2; ++bt) acc[mt][bt] = (f32x4){0.f, 0.f, 0.f, 0.f};

    __syncthreads();

    for (int s = 0; s < 16; ++s) {
        const int buf = s & 1;
        if (s < 15) {
            async16(agp0, &Al[buf ^ 1][w * 16 * 32]);
            async16(agp1, &Al[buf ^ 1][(64 + w * 16) * 32]);
            async16(bgp, &Bl[buf ^ 1][w * 16 * 32]);
            agp0 += 32; agp1 += 32; bgp += 32;
        }
        const char* Ab = (const char*)&Al[buf][0];
        const char* Bb = (const char*)&Bl[buf][0];
        bf16x8 af[4], bfr[2];
#pragma unroll
        for (int mt = 0; mt < 4; ++mt)
            af[mt] = *(const bf16x8*)(Ab + wm * 4096 + mt * 1024 + FOFF);
#pragma unroll
        for (int bt = 0; bt < 2; ++bt)
            bfr[bt] = *(const bf16x8*)(Bb + wn * 2048 + bt * 1024 + FOFF);
#pragma unroll
        for (int mt = 0; mt < 4; ++mt)
#pragma unroll
            for (int bt = 0; bt < 2; ++bt)
                acc[mt][bt] = MFMA16(af[mt], bfr[bt], acc[mt][bt]);
        __syncthreads();
    }

#pragma unroll
    for (int mt = 0; mt < 4; ++mt) {
        const int ch = m0 + wm * 64 + mt * 16 + quad * 4;
        float4 bv = *(const float4*)(pb + ch);
        float bvf[4] = {bv.x, bv.y, bv.z, bv.w};
#pragma unroll
        for (int bt = 0; bt < 2; ++bt) {
            int tok = n0 + wn * 32 + bt * 16 + lm;
#pragma unroll
            for (int r = 0; r < 4; ++r)
                out[(size_t)(ch + r) * 4096 + tok] = acc[mt][bt][r] + bvf[r];
        }
    }
}

// ---------------------------------------------------------------------------
// Flash attention v9: R4 base (best measured: 48 us) + IN-WAVE 2-TILE
// SOFTWARE PIPELINE (T15). R9 post-mortem: v8's barrier variant at 1 bl/CU
// was latency-bound (63 us, MfmaUtil 20%); across 9 rounds every config
// with <=512 MB L2 traffic lands at 48-63 us because the per-step serial
// chain ds_read->QK->exp2->pack->PV exposes ~3000 cyc/step with only
// 2 waves/SIMD to overlap. HK/AITER attn runs at the same occupancy but
// pipelines tiles IN-WAVE. v9 = R4 byte-identical (head-clustered grid 512,
// 256 thr, 4 private key-quarter waves, K+V LDS dbuf, no in-loop barriers,
// same vmcnt ledger) except the body computes PV of tile t-1 (from
// loop-carried bb/V regs, fully independent instructions) alongside QK+exp
// of tile t -> the MFMA pipe fills the exp2/pack latency. +32 loop-carried
// regs (~210 total), cap 256 at launch_bounds(256,2) (LDS-limited to 2
// blocks/CU anyway) -> no spill. Peeled body0 (QK only) + epilogue PV_31.
// WRITE_SIZE ~4 MB is the no-spill sentinel.
// ---------------------------------------------------------------------------
#define WAITVM(N) asm volatile("s_waitcnt vmcnt(" #N ")" ::: "memory")

__global__ __launch_bounds__(256, 2) void flash_attn(const u16* __restrict__ Qt,
                                                     const u16* __restrict__ Kt,
                                                     const u16* __restrict__ Vp,
                                                     const float* __restrict__ lqw2g,
                                                     u16* __restrict__ Ot) {
    __shared__ __align__(16) char smem[65536];

    const int tid = threadIdx.x;
    const int w = tid >> 6, lane = tid & 63;         // w = 0..3 (key quarter)
    const int quad = lane >> 4, lm = lane & 15;
    const int bid = blockIdx.x;
    const int h = bid & 7, hq = h * 64;              // head -> XCD cluster
    const int q0 = (bid >> 3) * 64;
    const int kstart = w * 1024;

    char* kvw = smem + w * 16384;                    // private [buf][K 4KB|V 4KB]

    // staging lane addressing (XOR swizzle at global source, LDS linear)
    const int srow = lane >> 3;                      // 0..7
    const int schunk = (lane & 7) ^ srow;
    const u16* kg = Kt + (size_t)(kstart + srow) * 512 + hq + schunk * 8;
    const u16* vg = Vp + (size_t)(hq + 2 * srow + (schunk >> 2)) * 4096 +
                    kstart + (schunk & 3) * 8;

    // Q fragments: 4 subtiles x 2 d-halves (8 vmem loads)
    bf16x8 bq0[4], bq1[4];
#pragma unroll
    for (int s = 0; s < 4; ++s) {
        const u16* qb = Qt + (size_t)(q0 + s * 16 + lm) * 512 + hq + quad * 8;
        bq0[s] = ldg8(qb);
        bq1[s] = ldg8(qb + 32);
    }

    // bias prefetch registers (2 vmem loads)
    f32x4 breg0 = *(const f32x4*)(lqw2g + kstart + quad * 4);
    f32x4 breg1 = *(const f32x4*)(lqw2g + kstart + 16 + quad * 4);
    const float* bptr = lqw2g + kstart + 32 + quad * 4;

    // fragment read offsets (proven layouts)
    const int A0 = lm * 128 + ((quad ^ (lm & 7)) << 4);       // K, d 0..31
    const int A1 = A0 ^ 64;                                   // K, d 32..63
    const int AV = (lm >> 1) * 128 +
                   (((4 * (lm & 1) + quad) ^ ((lm >> 1) & 7)) << 4);

#define STAGEBLK(DST)                                                          \
    {                                                                          \
        char* nb = (DST);                                                      \
        async16(kg, nb);                                                       \
        async16(kg + 8 * 512, nb + 1024);                                      \
        async16(kg + 16 * 512, nb + 2048);                                     \
        async16(kg + 24 * 512, nb + 3072);                                     \
        async16(vg, nb + 4096);                                                \
        async16(vg + (size_t)16 * 4096, nb + 5120);                            \
        async16(vg + (size_t)32 * 4096, nb + 6144);                            \
        async16(vg + (size_t)48 * 4096, nb + 7168);                            \
        kg += 32 * 512; vg += 32;                                              \
    }

    // stage tiles 0 and 1
    STAGEBLK(kvw)
    STAGEBLK(kvw + 8192)

    union { u32 u[4]; bf16x8 v; } onesu;
    onesu.u[0] = onesu.u[1] = onesu.u[2] = onesu.u[3] = 0x3F803F80u;
    const bf16x8 onesv = onesu.v;

    f32x4 acc_o[4][4];                                // [d-group][q-sub]
#pragma unroll
    for (int mt = 0; mt < 4; ++mt)
#pragma unroll
        for (int s = 0; s < 4; ++s) acc_o[mt][s] = (f32x4){0.f, 0.f, 0.f, 0.f};
    f32x4 acc_l[4];
#pragma unroll
    for (int s = 0; s < 4; ++s) acc_l[s] = (f32x4){0.f, 0.f, 0.f, 0.f};

    // loop-carried pipeline state: P (bb) and V frags of the previous tile
    union { u32 u[4]; bf16x8 v; } pb_[4];
    bf16x8 pv0, pv1, pv2, pv3;
    int bufsel = 0;

#define BODY(WN, DOBIAS, DOSTAGE, DOPV)                                        \
    {                                                                          \
        WAITVM(WN);                                                            \
        const char* Kb = kvw + bufsel;                                         \
        const char* Vb = Kb + 4096;                                            \
        bf16x8 k00 = *(const bf16x8*)(Kb + A0);                                \
        bf16x8 k01 = *(const bf16x8*)(Kb + A1);                                \
        bf16x8 k10 = *(const bf16x8*)(Kb + 2048 + A0);                         \
        bf16x8 k11 = *(const bf16x8*)(Kb + 2048 + A1);                         \
        bf16x8 nv0 = *(const bf16x8*)(Vb + AV);                                \
        bf16x8 nv1 = *(const bf16x8*)(Vb + 1024 + AV);                         \
        bf16x8 nv2 = *(const bf16x8*)(Vb + 2048 + AV);                         \
        bf16x8 nv3 = *(const bf16x8*)(Vb + 3072 + AV);                         \
        if (DOPV) {                                                            \
            _Pragma("unroll")                                                  \
            for (int s = 0; s < 4; ++s) {                                      \
                acc_o[0][s] = MFMA16(pv0, pb_[s].v, acc_o[0][s]);              \
                acc_o[1][s] = MFMA16(pv1, pb_[s].v, acc_o[1][s]);              \
                acc_o[2][s] = MFMA16(pv2, pb_[s].v, acc_o[2][s]);              \
                acc_o[3][s] = MFMA16(pv3, pb_[s].v, acc_o[3][s]);              \
                acc_l[s] = MFMA16(onesv, pb_[s].v, acc_l[s]);                  \
            }                                                                  \
        }                                                                      \
        _Pragma("unroll")                                                      \
        for (int s = 0; s < 4; ++s) {                                          \
            f32x4 a = MFMA16(k00, bq0[s], breg0);                              \
            a = MFMA16(k01, bq1[s], a);                                        \
            pb_[s].u[0] = pack2(EXP2F(a[0]), EXP2F(a[1]));                     \
            pb_[s].u[1] = pack2(EXP2F(a[2]), EXP2F(a[3]));                     \
        }                                                                      \
        _Pragma("unroll")                                                      \
        for (int s = 0; s < 4; ++s) {                                          \
            f32x4 c = MFMA16(k10, bq0[s], breg1);                              \
            c = MFMA16(k11, bq1[s], c);                                        \
            pb_[s].u[2] = pack2(EXP2F(c[0]), EXP2F(c[1]));                     \
            pb_[s].u[3] = pack2(EXP2F(c[2]), EXP2F(c[3]));                     \
        }                                                                      \
        if (DOBIAS) {                                                          \
            breg0 = *(const f32x4*)(bptr);                                     \
            breg1 = *(const f32x4*)(bptr + 16);                                \
            bptr += 32;                                                        \
        }                                                                      \
        pv0 = nv0; pv1 = nv1; pv2 = nv2; pv3 = nv3;                            \
        if (DOSTAGE) STAGEBLK(kvw + bufsel)                                    \
        bufsel ^= 8192;                                                        \
    }

    BODY(8, true, true, false)                 // t = 0: QK only (peel)
    for (int t = 1; t < 30; ++t)
        BODY(10, true, true, true)             // t = 1..29: PV_{t-1} + QK_t
    BODY(10, true, false, true)                // t = 30 (bias_31, no stage)
    BODY(2, false, false, true)                // t = 31

#undef BODY
#undef STAGEBLK

    // epilogue: PV for tile 31
#pragma unroll
    for (int s = 0; s < 4; ++s) {
        acc_o[0][s] = MFMA16(pv0, pb_[s].v, acc_o[0][s]);
        acc_o[1][s] = MFMA16(pv1, pb_[s].v, acc_o[1][s]);
        acc_o[2][s] = MFMA16(pv2, pb_[s].v, acc_o[2][s]);
        acc_o[3][s] = MFMA16(pv3, pb_[s].v, acc_o[3][s]);
        acc_l[s] = MFMA16(onesv, pb_[s].v, acc_l[s]);
    }

    // ---- split-K merge: pure add (max-free softmax), 4-way ----
    __syncthreads();                           // staging LDS now dead
    float* mbuf = (float*)smem;
    if (w != 0) {
        float* ob = mbuf + (w - 1) * 4096;     // 64 q x 64 d fp32
#pragma unroll
        for (int s = 0; s < 4; ++s) {
            const int r = s * 16 + lm;
#pragma unroll
            for (int mt = 0; mt < 4; ++mt) {
                const int sl = (mt * 4 + quad) ^ lm;
                *(f32x4*)(ob + r * 64 + sl * 4) = acc_o[mt][s];
            }
        }
        if (quad == 0) {
#pragma unroll
            for (int s = 0; s < 4; ++s)
                mbuf[12288 + (w - 1) * 64 + s * 16 + lm] = acc_l[s][0];
        }
    }
    __syncthreads();
    if (w != 0) return;

#pragma unroll
    for (int s = 0; s < 4; ++s) {
        const int r = s * 16 + lm;
        float lsum = acc_l[s][0];
#pragma unroll
        for (int p = 0; p < 3; ++p)
            lsum += mbuf[12288 + p * 64 + r];
        const float inv = 1.0f / lsum;
#pragma unroll
        for (int mt = 0; mt < 4; ++mt) {
            const int sl = (mt * 4 + quad) ^ lm;
            f32x4 o = acc_o[mt][s];
#pragma unroll
            for (int p = 0; p < 3; ++p)
                o += *(const f32x4*)(mbuf + p * 4096 + r * 64 + sl * 4);
            u16x4 pkv;
#pragma unroll
            for (int r2 = 0; r2 < 4; ++r2)
                pkv[r2] = f2bf(o[r2] * inv);
            *reinterpret_cast<u16x4*>(Ot + (size_t)(q0 + r) * 512 +
                                      hq + mt * 16 + quad * 4) = pkv;
        }
    }
}

// ---------------------------------------------------------------------------
extern "C" void kernel_launch(void* const* d_in, const int* in_sizes, int n_in,
                              void* d_out, int out_size, void* d_ws, size_t ws_size,
                              hipStream_t stream) {
    (void)in_sizes; (void)n_in; (void)out_size; (void)ws_size;
    const float* X   = (const float*)d_in[0];
    const float* qw  = (const float*)d_in[1];
    const float* qb  = (const float*)d_in[2];
    const float* kw  = (const float*)d_in[3];
    const float* kb  = (const float*)d_in[4];
    const float* vw  = (const float*)d_in[5];
    const float* vb  = (const float*)d_in[6];
    const float* pw  = (const float*)d_in[7];
    const float* pb  = (const float*)d_in[8];
    const float* lqw = (const float*)d_in[9];

    const size_t E = (size_t)4096 * 512;
    const size_t WE = (size_t)512 * 512;
    u16* Xt    = (u16*)d_ws;
    u16* Qt    = Xt + E;
    u16* Kt    = Qt + E;
    u16* Vp    = Kt + E;
    u16* Wqkv  = Vp + E;          // 1536 x 512 stacked
    u16* Wp    = Wqkv + 3 * WE;
    float* lqw2g = (float*)(Wp + WE);   // 4096 fp32, 16B-aligned
    u16* Ot    = Xt;              // reuse (dead after qkv)

    prep<<<dim3(64, 13), dim3(256), 0, stream>>>(X, Xt, qw, kw, vw, pw,
                                                 Wqkv, Wp, lqw, lqw2g);
    qkv_gemm<<<dim3(32, 12), dim3(512), 0, stream>>>(Wqkv, Xt, qb, kb, vb, Qt, Kt, Vp);
    flash_attn<<<dim3(512), dim3(256), 0, stream>>>(Qt, Kt, Vp, lqw2g, Ot);
    out_gemm<<<dim3(64, 4), dim3(256), 0, stream>>>(Wp, Ot, pb, (float*)d_out);
}

// Round 11
// 77.345 us; speedup vs baseline: 2.5471x; 1.0052x over previous
//
#include <hip/hip_runtime.h>

typedef unsigned short u16;
typedef unsigned int u32;
typedef __bf16 bf16x8 __attribute__((ext_vector_type(8)));
typedef float f32x4 __attribute__((ext_vector_type(4)));
typedef unsigned short u16x4 __attribute__((ext_vector_type(4)));

#define LOG2E 1.4426950408889634f

#if __has_builtin(__builtin_amdgcn_exp2f)
#define EXP2F(x) __builtin_amdgcn_exp2f(x)
#else
#define EXP2F(x) exp2f(x)
#endif

__device__ __forceinline__ u16 f2bf(float f) {
    union { float f; u32 u; } a; a.f = f;
    u32 u = a.u;
    u += 0x7FFFu + ((u >> 16) & 1u);   // RNE (finite inputs)
    return (u16)(u >> 16);
}
__device__ __forceinline__ bf16x8 ldg8(const u16* p) {
    return *reinterpret_cast<const bf16x8*>(p);
}
#if __has_builtin(__builtin_amdgcn_cvt_pk_bf16_f32)
__device__ __forceinline__ u32 pack2(float a, float b) {
    auto r = __builtin_amdgcn_cvt_pk_bf16_f32(a, b);   // v_cvt_pk_bf16_f32
    return __builtin_bit_cast(u32, r);
}
#else
__device__ __forceinline__ u32 pack2(float a, float b) {
    u32 ua = __float_as_uint(a) + 0x8000u;
    u32 ub = __float_as_uint(b) + 0x8000u;
    return __builtin_amdgcn_perm(ub, ua, 0x07060302);
}
#endif
// async global -> LDS, 16 B per lane. LDS dest = wave-uniform base + lane*16.
__device__ __forceinline__ void async16(const void* g, void* l) {
    __builtin_amdgcn_global_load_lds(
        (const __attribute__((address_space(1))) u32*)g,
        (__attribute__((address_space(3))) u32*)l, 16, 0, 0);
}

#define MFMA16(a, b, c) __builtin_amdgcn_mfma_f32_16x16x32_bf16((a), (b), (c), 0, 0, 0)

// ---------------------------------------------------------------------------
// Fused prep: y<8 -> transpose X tile; y in 8..11 -> pack weight matrix;
// y==12 -> lqw * log2(e) into global fp32 (4 blocks). Grid (64, 13).
// ---------------------------------------------------------------------------
__global__ __launch_bounds__(256) void prep(const float* __restrict__ X,
                                            u16* __restrict__ Xt,
                                            const float* __restrict__ s0,
                                            const float* __restrict__ s1,
                                            const float* __restrict__ s2,
                                            const float* __restrict__ s3,
                                            u16* __restrict__ Wqkv,
                                            u16* __restrict__ Wp,
                                            const float* __restrict__ lqw,
                                            float* __restrict__ lqw2g) {
    __shared__ u16 tile[64][65];
    const int tid = threadIdx.x;
    const int y = blockIdx.y;

    if (y < 8) {                                  // transpose 64x64 tile
        const int t0 = blockIdx.x * 64;
        const int c0 = y * 64;
#pragma unroll
        for (int i = 0; i < 16; ++i) {
            int idx = tid + i * 256;
            int r = idx >> 6, cc = idx & 63;
            tile[r][cc] = f2bf(X[(size_t)(c0 + r) * 4096 + t0 + cc]);
        }
        __syncthreads();
#pragma unroll
        for (int i = 0; i < 16; ++i) {
            int idx = tid + i * 256;
            int tr = idx >> 6, cc = idx & 63;
            Xt[(size_t)(t0 + tr) * 512 + c0 + cc] = tile[cc][tr];
        }
    } else if (y < 12) {                          // pack one 512x512 weight
        const int m = y - 8;
        const float* s = (m == 0) ? s0 : (m == 1) ? s1 : (m == 2) ? s2 : s3;
        u16* d = (m == 3) ? Wp : Wqkv + (size_t)m * 262144;
#pragma unroll
        for (int j = 0; j < 4; ++j) {
            int i = blockIdx.x * 1024 + j * 256 + tid;
            float4 v = reinterpret_cast<const float4*>(s)[i];
            u16x4 o;
            o[0] = f2bf(v.x); o[1] = f2bf(v.y); o[2] = f2bf(v.z); o[3] = f2bf(v.w);
            reinterpret_cast<u16x4*>(d)[i] = o;
        }
    } else {                                      // lqw * LOG2E (1024 float4)
        if (blockIdx.x < 4) {
            int i = blockIdx.x * 256 + tid;
            float4 v = reinterpret_cast<const float4*>(lqw)[i];
            v.x *= LOG2E; v.y *= LOG2E; v.z *= LOG2E; v.w *= LOG2E;
            reinterpret_cast<float4*>(lqw2g)[i] = v;
        }
    }
}

// ---------------------------------------------------------------------------
// Fused QKV GEMM, LDS-staged. Q written token-major (unchanged). K and V are
// written DIRECTLY in the flash kernel's staged-LDS image, tiled as
// KV[head][tile 0..127][K 4KB | V 4KB] (8 KB per 32-key tile), so flash
// staging becomes an identity copy (8 fully-coalesced 1KB async16 per tile).
// The image replicates the R1/R4-proven LDS layout byte-for-byte:
//   K: lds[key][c]16B = K[tok][d chunk c ^ (key&7)]          (XOR swizzle)
//   V: lds[rl][c]16B  = Vp_old[D][col], rl=(D>>4)*8+((D>>1)&7),
//      c=((D>>1)&7)^(4*(D&1)+kc)  with col = the OLD Vp column permutation
//      (preserves the proven P<->V k-slot correspondence).
// ---------------------------------------------------------------------------
__global__ __launch_bounds__(512, 2) void qkv_gemm(const u16* __restrict__ Wqkv,
                                                   const u16* __restrict__ Xt,
                                                   const float* __restrict__ qb,
                                                   const float* __restrict__ kb,
                                                   const float* __restrict__ vb,
                                                   u16* __restrict__ Qt,
                                                   u16* __restrict__ KV) {
    __shared__ __align__(16) u16 Al[2][128 * 32];
    __shared__ __align__(16) u16 Bl[2][128 * 32];

    const int tid = threadIdx.x;
    const int w = tid >> 6, lane = tid & 63;
    const int quad = lane >> 4, lm = lane & 15;
    const int wm = w & 1, wn = w >> 1;
    const int n0 = blockIdx.x * 128;
    const int my = blockIdx.y;
    const int m0 = my * 128;

    const int arow = lane >> 2;
    const int sch = (lane & 3) ^ ((lane >> 3) & 3);   // source chunk (XOR on row>>1)
    const u16* agp = Wqkv + (size_t)(m0 + w * 16 + arow) * 512 + sch * 8;
    const u16* bgp = Xt + (size_t)(n0 + w * 16 + arow) * 512 + sch * 8;

    async16(agp, &Al[0][w * 16 * 32]);
    async16(bgp, &Bl[0][w * 16 * 32]);
    agp += 32; bgp += 32;

    const int FOFF = lm * 64 + ((quad ^ ((lm >> 1) & 3)) << 4);

    f32x4 acc[4][2];
#pragma unroll
    for (int mt = 0; mt < 4; ++mt)
#pragma unroll
        for (int bt = 0; bt < 2; ++bt) acc[mt][bt] = (f32x4){0.f, 0.f, 0.f, 0.f};

    __syncthreads();

    for (int s = 0; s < 16; ++s) {
        const int buf = s & 1;
        if (s < 15) {
            async16(agp, &Al[buf ^ 1][w * 16 * 32]);
            async16(bgp, &Bl[buf ^ 1][w * 16 * 32]);
            agp += 32; bgp += 32;
        }
        const char* Ab = (const char*)&Al[buf][0];
        const char* Bb = (const char*)&Bl[buf][0];
        bf16x8 af[4], bfr[2];
#pragma unroll
        for (int mt = 0; mt < 4; ++mt)
            af[mt] = *(const bf16x8*)(Ab + wm * 4096 + mt * 1024 + FOFF);
#pragma unroll
        for (int bt = 0; bt < 2; ++bt)
            bfr[bt] = *(const bf16x8*)(Bb + wn * 2048 + bt * 1024 + FOFF);
#pragma unroll
        for (int mt = 0; mt < 4; ++mt)
#pragma unroll
            for (int bt = 0; bt < 2; ++bt)
                acc[mt][bt] = MFMA16(af[mt], bfr[bt], acc[mt][bt]);
        __syncthreads();
    }

    const int mat = my >> 2;                     // 0=Q, 1=K, 2=V
    const float* bias = (mat == 0) ? qb : (mat == 1) ? kb : vb;
    const int chbase = (my & 3) * 128 + wm * 64 + quad * 4;

    if (mat == 0) {
        const float sc = 0.125f * LOG2E;
#pragma unroll
        for (int mt = 0; mt < 4; ++mt) {
            const int ch = chbase + mt * 16;
            float4 bv = *(const float4*)(bias + ch);
            float bvf[4] = {bv.x, bv.y, bv.z, bv.w};
#pragma unroll
            for (int bt = 0; bt < 2; ++bt) {
                int tok = n0 + wn * 32 + bt * 16 + lm;
                u16x4 pk;
#pragma unroll
                for (int r = 0; r < 4; ++r)
                    pk[r] = f2bf((acc[mt][bt][r] + bvf[r]) * sc);
                *(u16x4*)(Qt + (size_t)tok * 512 + ch) = pk;
            }
        }
    } else if (mat == 1) {
        // K -> tiled image: KV[(hh*128+t)*4096 + key*64 + c*8 + e0], c = cp^(key&7)
#pragma unroll
        for (int mt = 0; mt < 4; ++mt) {
            const int ch = chbase + mt * 16;
            float4 bv = *(const float4*)(bias + ch);
            float bvf[4] = {bv.x, bv.y, bv.z, bv.w};
            const int hh = ch >> 6;
            const int D0 = ch & 63;              // mt*16 + quad*4
            const int cp = D0 >> 3;
            const int e0 = D0 & 7;               // (quad&1)*4
#pragma unroll
            for (int bt = 0; bt < 2; ++bt) {
                int tok = n0 + wn * 32 + bt * 16 + lm;
                int t = tok >> 5, key = tok & 31;
                int c = cp ^ (key & 7);
                u16x4 pk;
#pragma unroll
                for (int r = 0; r < 4; ++r)
                    pk[r] = f2bf(acc[mt][bt][r] + bvf[r]);
                *(u16x4*)(KV + (size_t)(hh * 128 + t) * 4096 + key * 64 + c * 8 + e0) = pk;
            }
        }
    } else {
        // V -> tiled image (+2048 u16), pair-row layout with old col permutation
#pragma unroll
        for (int mt = 0; mt < 4; ++mt) {
            const int ch = chbase + mt * 16;
            float4 bv = *(const float4*)(bias + ch);
            float bvf[4] = {bv.x, bv.y, bv.z, bv.w};
            const int hh = ch >> 6;
            const int D0 = ch & 63;
#pragma unroll
            for (int bt = 0; bt < 2; ++bt) {
                int g = bt * 16 + lm;
                int key2 = 8 * ((g >> 2) & 3) + 4 * ((g >> 4) & 1) + (g & 3);
                int t = (n0 >> 5) + wn;          // (old col) >> 5
                int kc = key2 >> 3, ke = key2 & 7;
                u16* vdst = KV + (size_t)(hh * 128 + t) * 4096 + 2048 + ke;
#pragma unroll
                for (int r = 0; r < 4; ++r) {
                    int D = D0 + r;
                    int rl = (D >> 4) * 8 + ((D >> 1) & 7);
                    int c = ((D >> 1) & 7) ^ (4 * (D & 1) + kc);
                    vdst[rl * 64 + c * 8] = f2bf(acc[mt][bt][r] + bvf[r]);
                }
            }
        }
    }
}

// ---------------------------------------------------------------------------
// Output projection, LDS-staged (unchanged, known-good).
// ---------------------------------------------------------------------------
__global__ __launch_bounds__(256, 2) void out_gemm(const u16* __restrict__ Wp,
                                                   const u16* __restrict__ Ot,
                                                   const float* __restrict__ pb,
                                                   float* __restrict__ out) {
    __shared__ __align__(16) u16 Al[2][128 * 32];
    __shared__ __align__(16) u16 Bl[2][64 * 32];

    const int tid = threadIdx.x;
    const int w = tid >> 6, lane = tid & 63;
    const int quad = lane >> 4, lm = lane & 15;
    const int wm = w & 1, wn = w >> 1;
    const int n0 = blockIdx.x * 64;
    const int m0 = blockIdx.y * 128;

    const int arow = lane >> 2;
    const int sch = (lane & 3) ^ ((lane >> 3) & 3);
    const u16* agp0 = Wp + (size_t)(m0 + w * 16 + arow) * 512 + sch * 8;
    const u16* agp1 = agp0 + (size_t)64 * 512;
    const u16* bgp = Ot + (size_t)(n0 + w * 16 + arow) * 512 + sch * 8;

    async16(agp0, &Al[0][w * 16 * 32]);
    async16(agp1, &Al[0][(64 + w * 16) * 32]);
    async16(bgp, &Bl[0][w * 16 * 32]);
    agp0 += 32; agp1 += 32; bgp += 32;

    const int FOFF = lm * 64 + ((quad ^ ((lm >> 1) & 3)) << 4);

    f32x4 acc[4][2];
#pragma unroll
    for (int mt = 0; mt < 4; ++mt)
#pragma unroll
        for (int bt = 0; bt < 2; ++bt) acc[mt][bt] = (f32x4){0.f, 0.f, 0.f, 0.f};

    __syncthreads();

    for (int s = 0; s < 16; ++s) {
        const int buf = s & 1;
        if (s < 15) {
            async16(agp0, &Al[buf ^ 1][w * 16 * 32]);
            async16(agp1, &Al[buf ^ 1][(64 + w * 16) * 32]);
            async16(bgp, &Bl[buf ^ 1][w * 16 * 32]);
            agp0 += 32; agp1 += 32; bgp += 32;
        }
        const char* Ab = (const char*)&Al[buf][0];
        const char* Bb = (const char*)&Bl[buf][0];
        bf16x8 af[4], bfr[2];
#pragma unroll
        for (int mt = 0; mt < 4; ++mt)
            af[mt] = *(const bf16x8*)(Ab + wm * 4096 + mt * 1024 + FOFF);
#pragma unroll
        for (int bt = 0; bt < 2; ++bt)
            bfr[bt] = *(const bf16x8*)(Bb + wn * 2048 + bt * 1024 + FOFF);
#pragma unroll
        for (int mt = 0; mt < 4; ++mt)
#pragma unroll
            for (int bt = 0; bt < 2; ++bt)
                acc[mt][bt] = MFMA16(af[mt], bfr[bt], acc[mt][bt]);
        __syncthreads();
    }

#pragma unroll
    for (int mt = 0; mt < 4; ++mt) {
        const int ch = m0 + wm * 64 + mt * 16 + quad * 4;
        float4 bv = *(const float4*)(pb + ch);
        float bvf[4] = {bv.x, bv.y, bv.z, bv.w};
#pragma unroll
        for (int bt = 0; bt < 2; ++bt) {
            int tok = n0 + wn * 32 + bt * 16 + lm;
#pragma unroll
            for (int r = 0; r < 4; ++r)
                out[(size_t)(ch + r) * 4096 + tok] = acc[mt][bt][r] + bvf[r];
        }
    }
}

// ---------------------------------------------------------------------------
// Flash attention v10: R10 structure + IDENTITY STAGING from pre-tiled KV
// + s_setprio around the MFMA cluster (T5).
// R10 post-mortem: 2-tile pipeline was a no-op (compiler had already
// pipelined; same VGPR count). All 10 rounds obey: time = staged L2 bytes /
// ~10.7 TB/s (512MB->48us, 1GB->104, 2GB->176) — L2-request-rate bound:
// K staging = scattered 128B segments (rows 1KB apart), V = scattered 64B
// segments. v10: qkv_gemm pre-bakes the exact LDS image into tiled
// KV[h][tile][8KB], so each stage op is a single fully-coalesced 1KB burst
// with a linearly-advancing source (33% fewer L2 ops, all 128B-sequential).
// Everything else (barrier-free private quarters, vmcnt ledger 8/10/10/2,
// fragment offsets, merge) is byte-identical to R10. absmax must be
// bit-identical to R10 — any change flags a layout bug.
// ---------------------------------------------------------------------------
#define WAITVM(N) asm volatile("s_waitcnt vmcnt(" #N ")" ::: "memory")

__global__ __launch_bounds__(256, 2) void flash_attn(const u16* __restrict__ Qt,
                                                     const u16* __restrict__ KV,
                                                     const float* __restrict__ lqw2g,
                                                     u16* __restrict__ Ot) {
    __shared__ __align__(16) char smem[65536];

    const int tid = threadIdx.x;
    const int w = tid >> 6, lane = tid & 63;         // w = 0..3 (key quarter)
    const int quad = lane >> 4, lm = lane & 15;
    const int bid = blockIdx.x;
    const int h = bid & 7, hq = h * 64;              // head -> XCD cluster
    const int q0 = (bid >> 3) * 64;
    const int kstart = w * 1024;

    char* kvw = smem + w * 16384;                    // private [buf][K 4KB|V 4KB]

    // identity staging source: tile = 8 KB, lane reads its own 16 B
    const u16* kvs = KV + ((size_t)(h * 128 + w * 32) * 4096) + (size_t)lane * 8;

    // Q fragments: 4 subtiles x 2 d-halves (8 vmem loads)
    bf16x8 bq0[4], bq1[4];
#pragma unroll
    for (int s = 0; s < 4; ++s) {
        const u16* qb = Qt + (size_t)(q0 + s * 16 + lm) * 512 + hq + quad * 8;
        bq0[s] = ldg8(qb);
        bq1[s] = ldg8(qb + 32);
    }

    // bias prefetch registers (2 vmem loads)
    f32x4 breg0 = *(const f32x4*)(lqw2g + kstart + quad * 4);
    f32x4 breg1 = *(const f32x4*)(lqw2g + kstart + 16 + quad * 4);
    const float* bptr = lqw2g + kstart + 32 + quad * 4;

    // fragment read offsets (proven layouts, LDS image unchanged)
    const int A0 = lm * 128 + ((quad ^ (lm & 7)) << 4);       // K, d 0..31
    const int A1 = A0 ^ 64;                                   // K, d 32..63
    const int AV = (lm >> 1) * 128 +
                   (((4 * (lm & 1) + quad) ^ ((lm >> 1) & 7)) << 4);

#define STAGEBLK(DST)                                                          \
    {                                                                          \
        char* nb = (DST);                                                      \
        async16(kvs, nb);                                                      \
        async16(kvs + 512, nb + 1024);                                         \
        async16(kvs + 1024, nb + 2048);                                        \
        async16(kvs + 1536, nb + 3072);                                        \
        async16(kvs + 2048, nb + 4096);                                        \
        async16(kvs + 2560, nb + 5120);                                        \
        async16(kvs + 3072, nb + 6144);                                        \
        async16(kvs + 3584, nb + 7168);                                        \
        kvs += 4096;                                                           \
    }

    // stage tiles 0 and 1
    STAGEBLK(kvw)
    STAGEBLK(kvw + 8192)

    union { u32 u[4]; bf16x8 v; } onesu;
    onesu.u[0] = onesu.u[1] = onesu.u[2] = onesu.u[3] = 0x3F803F80u;
    const bf16x8 onesv = onesu.v;

    f32x4 acc_o[4][4];                                // [d-group][q-sub]
#pragma unroll
    for (int mt = 0; mt < 4; ++mt)
#pragma unroll
        for (int s = 0; s < 4; ++s) acc_o[mt][s] = (f32x4){0.f, 0.f, 0.f, 0.f};
    f32x4 acc_l[4];
#pragma unroll
    for (int s = 0; s < 4; ++s) acc_l[s] = (f32x4){0.f, 0.f, 0.f, 0.f};

    // loop-carried pipeline state: P (bb) and V frags of the previous tile
    union { u32 u[4]; bf16x8 v; } pb_[4];
    bf16x8 pv0, pv1, pv2, pv3;
    int bufsel = 0;

#define BODY(WN, DOBIAS, DOSTAGE, DOPV)                                        \
    {                                                                          \
        WAITVM(WN);                                                            \
        const char* Kb = kvw + bufsel;                                         \
        const char* Vb = Kb + 4096;                                            \
        bf16x8 k00 = *(const bf16x8*)(Kb + A0);                                \
        bf16x8 k01 = *(const bf16x8*)(Kb + A1);                                \
        bf16x8 k10 = *(const bf16x8*)(Kb + 2048 + A0);                         \
        bf16x8 k11 = *(const bf16x8*)(Kb + 2048 + A1);                         \
        bf16x8 nv0 = *(const bf16x8*)(Vb + AV);                                \
        bf16x8 nv1 = *(const bf16x8*)(Vb + 1024 + AV);                         \
        bf16x8 nv2 = *(const bf16x8*)(Vb + 2048 + AV);                         \
        bf16x8 nv3 = *(const bf16x8*)(Vb + 3072 + AV);                         \
        __builtin_amdgcn_s_setprio(1);                                         \
        if (DOPV) {                                                            \
            _Pragma("unroll")                                                  \
            for (int s = 0; s < 4; ++s) {                                      \
                acc_o[0][s] = MFMA16(pv0, pb_[s].v, acc_o[0][s]);              \
                acc_o[1][s] = MFMA16(pv1, pb_[s].v, acc_o[1][s]);              \
                acc_o[2][s] = MFMA16(pv2, pb_[s].v, acc_o[2][s]);              \
                acc_o[3][s] = MFMA16(pv3, pb_[s].v, acc_o[3][s]);              \
                acc_l[s] = MFMA16(onesv, pb_[s].v, acc_l[s]);                  \
            }                                                                  \
        }                                                                      \
        _Pragma("unroll")                                                      \
        for (int s = 0; s < 4; ++s) {                                          \
            f32x4 a = MFMA16(k00, bq0[s], breg0);                              \
            a = MFMA16(k01, bq1[s], a);                                        \
            pb_[s].u[0] = pack2(EXP2F(a[0]), EXP2F(a[1]));                     \
            pb_[s].u[1] = pack2(EXP2F(a[2]), EXP2F(a[3]));                     \
        }                                                                      \
        _Pragma("unroll")                                                      \
        for (int s = 0; s < 4; ++s) {                                          \
            f32x4 c = MFMA16(k10, bq0[s], breg1);                              \
            c = MFMA16(k11, bq1[s], c);                                        \
            pb_[s].u[2] = pack2(EXP2F(c[0]), EXP2F(c[1]));                     \
            pb_[s].u[3] = pack2(EXP2F(c[2]), EXP2F(c[3]));                     \
        }                                                                      \
        __builtin_amdgcn_s_setprio(0);                                         \
        if (DOBIAS) {                                                          \
            breg0 = *(const f32x4*)(bptr);                                     \
            breg1 = *(const f32x4*)(bptr + 16);                                \
            bptr += 32;                                                        \
        }                                                                      \
        pv0 = nv0; pv1 = nv1; pv2 = nv2; pv3 = nv3;                            \
        if (DOSTAGE) STAGEBLK(kvw + bufsel)                                    \
        bufsel ^= 8192;                                                        \
    }

    BODY(8, true, true, false)                 // t = 0: QK only (peel)
    for (int t = 1; t < 30; ++t)
        BODY(10, true, true, true)             // t = 1..29: PV_{t-1} + QK_t
    BODY(10, true, false, true)                // t = 30 (bias_31, no stage)
    BODY(2, false, false, true)                // t = 31

#undef BODY
#undef STAGEBLK

    // epilogue: PV for tile 31
#pragma unroll
    for (int s = 0; s < 4; ++s) {
        acc_o[0][s] = MFMA16(pv0, pb_[s].v, acc_o[0][s]);
        acc_o[1][s] = MFMA16(pv1, pb_[s].v, acc_o[1][s]);
        acc_o[2][s] = MFMA16(pv2, pb_[s].v, acc_o[2][s]);
        acc_o[3][s] = MFMA16(pv3, pb_[s].v, acc_o[3][s]);
        acc_l[s] = MFMA16(onesv, pb_[s].v, acc_l[s]);
    }

    // ---- split-K merge: pure add (max-free softmax), 4-way ----
    __syncthreads();                           // staging LDS now dead
    float* mbuf = (float*)smem;
    if (w != 0) {
        float* ob = mbuf + (w - 1) * 4096;     // 64 q x 64 d fp32
#pragma unroll
        for (int s = 0; s < 4; ++s) {
            const int r = s * 16 + lm;
#pragma unroll
            for (int mt = 0; mt < 4; ++mt) {
                const int sl = (mt * 4 + quad) ^ lm;
                *(f32x4*)(ob + r * 64 + sl * 4) = acc_o[mt][s];
            }
        }
        if (quad == 0) {
#pragma unroll
            for (int s = 0; s < 4; ++s)
                mbuf[12288 + (w - 1) * 64 + s * 16 + lm] = acc_l[s][0];
        }
    }
    __syncthreads();
    if (w != 0) return;

#pragma unroll
    for (int s = 0; s < 4; ++s) {
        const int r = s * 16 + lm;
        float lsum = acc_l[s][0];
#pragma unroll
        for (int p = 0; p < 3; ++p)
            lsum += mbuf[12288 + p * 64 + r];
        const float inv = 1.0f / lsum;
#pragma unroll
        for (int mt = 0; mt < 4; ++mt) {
            const int sl = (mt * 4 + quad) ^ lm;
            f32x4 o = acc_o[mt][s];
#pragma unroll
            for (int p = 0; p < 3; ++p)
                o += *(const f32x4*)(mbuf + p * 4096 + r * 64 + sl * 4);
            u16x4 pkv;
#pragma unroll
            for (int r2 = 0; r2 < 4; ++r2)
                pkv[r2] = f2bf(o[r2] * inv);
            *reinterpret_cast<u16x4*>(Ot + (size_t)(q0 + r) * 512 +
                                      hq + mt * 16 + quad * 4) = pkv;
        }
    }
}

// ---------------------------------------------------------------------------
extern "C" void kernel_launch(void* const* d_in, const int* in_sizes, int n_in,
                              void* d_out, int out_size, void* d_ws, size_t ws_size,
                              hipStream_t stream) {
    (void)in_sizes; (void)n_in; (void)out_size; (void)ws_size;
    const float* X   = (const float*)d_in[0];
    const float* qw  = (const float*)d_in[1];
    const float* qb  = (const float*)d_in[2];
    const float* kw  = (const float*)d_in[3];
    const float* kb  = (const float*)d_in[4];
    const float* vw  = (const float*)d_in[5];
    const float* vb  = (const float*)d_in[6];
    const float* pw  = (const float*)d_in[7];
    const float* pb  = (const float*)d_in[8];
    const float* lqw = (const float*)d_in[9];

    const size_t E = (size_t)4096 * 512;
    const size_t WE = (size_t)512 * 512;
    u16* Xt    = (u16*)d_ws;
    u16* Qt    = Xt + E;
    u16* KV    = Qt + E;          // 8 heads x 128 tiles x 8 KB = 8 MB (2E u16)
    u16* Wqkv  = KV + 2 * E;      // 1536 x 512 stacked
    u16* Wp    = Wqkv + 3 * WE;
    float* lqw2g = (float*)(Wp + WE);   // 4096 fp32, 16B-aligned
    u16* Ot    = Xt;              // reuse (dead after qkv)

    prep<<<dim3(64, 13), dim3(256), 0, stream>>>(X, Xt, qw, kw, vw, pw,
                                                 Wqkv, Wp, lqw, lqw2g);
    qkv_gemm<<<dim3(32, 12), dim3(512), 0, stream>>>(Wqkv, Xt, qb, kb, vb, Qt, KV);
    flash_attn<<<dim3(512), dim3(256), 0, stream>>>(Qt, KV, lqw2g, Ot);
    out_gemm<<<dim3(64, 4), dim3(256), 0, stream>>>(Wp, Ot, pb, (float*)d_out);
}